// Round 9
// baseline (2542.050 us; speedup 1.0000x reference)
//
#include <hip/hip_runtime.h>
#include <hip/hip_bf16.h>

#define T_STEPS 100
#define NG 4096
#define NP 512

typedef __bf16 bf16x8 __attribute__((ext_vector_type(8)));
typedef float f32x4 __attribute__((ext_vector_type(4)));

__device__ __forceinline__ f32x4 mfma_bf16(bf16x8 a, bf16x8 b, f32x4 c) {
  return __builtin_amdgcn_mfma_f32_16x16x32_bf16(a, b, c, 0, 0, 0);
}

// ---------------- f32 -> bf16 conversion, 8 elems/thread ----------------
__global__ __launch_bounds__(256) void cvt_bf16_kernel(const float* __restrict__ in,
                                                       __hip_bfloat16* __restrict__ out,
                                                       int n8) {
  int i = blockIdx.x * 256 + threadIdx.x;
  if (i >= n8) return;
  const float4* p = reinterpret_cast<const float4*>(in) + (size_t)i * 2;
  float4 f0 = p[0], f1 = p[1];
  union { __hip_bfloat16 h[8]; uint4 u; } z;
  z.h[0] = __float2bfloat16(f0.x); z.h[1] = __float2bfloat16(f0.y);
  z.h[2] = __float2bfloat16(f0.z); z.h[3] = __float2bfloat16(f0.w);
  z.h[4] = __float2bfloat16(f1.x); z.h[5] = __float2bfloat16(f1.y);
  z.h[6] = __float2bfloat16(f1.z); z.h[7] = __float2bfloat16(f1.w);
  *(reinterpret_cast<uint4*>(out) + i) = z.u;
}

// ---------------- encoder: h0 = p0 @ W_enc^T  -> bf16 -------------------
__global__ __launch_bounds__(256) void encoder_kernel(const float* __restrict__ p0,
                                                      const float* __restrict__ Wenc,
                                                      __hip_bfloat16* __restrict__ h0) {
  __shared__ float sp[64 * 129];
  const int tid = threadIdx.x;
  const int nb = blockIdx.x * 16;
  const int b = tid & 63;
  const int jg = tid >> 6;
  float acc[4] = {0.f, 0.f, 0.f, 0.f};
  for (int kc = 0; kc < NP; kc += 128) {
    __syncthreads();
    #pragma unroll
    for (int i = 0; i < 32; ++i) {
      int e = tid + i * 256;
      int bb = e >> 7, kk = e & 127;
      sp[bb * 129 + kk] = p0[bb * NP + kc + kk];
    }
    __syncthreads();
    for (int kk = 0; kk < 128; ++kk) {
      float pv = sp[b * 129 + kk];
      #pragma unroll
      for (int jj = 0; jj < 4; ++jj)
        acc[jj] += pv * Wenc[(size_t)(nb + jg * 4 + jj) * NP + kc + kk];
    }
  }
  #pragma unroll
  for (int jj = 0; jj < 4; ++jj)
    h0[(size_t)b * NG + nb + jg * 4 + jj] = __float2bfloat16(acc[jj]);
}

// ---------------- RNN GEMM, KQ=16: 1024 blocks (4/CU, 16 waves/CU) ------
// grid (64 ng, 16 kq), block 256 = 4 waves (ms = w>>1: 32 b-rows; ns = w&1:
// 32 n-cols). Wave 32b x 32n x 256k, 2x2 frags = 4 indep MFMA chains.
// ALL 16 A-loads issued upfront into regs (cross-XCD ~900cy latency
// amortized over whole loop); B (L2-resident Wh) 1-deep ping.
__global__ __launch_bounds__(256, 4) void rnn_gemm16_kernel(
    const __hip_bfloat16* __restrict__ A, int strideA,
    const __hip_bfloat16* __restrict__ Wh,
    float* __restrict__ zpart) {
  const int lane = threadIdx.x & 63;
  const int w = threadIdx.x >> 6;
  const int ms = w >> 1, ns = w & 1;
  const int ng = blockIdx.x, kq = blockIdx.y;
  const int r = lane & 15;
  const int kg = lane >> 4;
  const int kbase = kq * 256 + kg * 8;
  const int n0 = ng * 64 + ns * 32;

  const __hip_bfloat16* pA0 = A + (size_t)(ms * 32 + r) * strideA + kbase;
  const __hip_bfloat16* pA1 = pA0 + (size_t)16 * strideA;
  const __hip_bfloat16* pB0 = Wh + (size_t)(n0 + r) * NG + kbase;
  const __hip_bfloat16* pB1 = pB0 + (size_t)16 * NG;

  // upfront A prefetch: 16 loads in flight
  bf16x8 Ar0[8], Ar1[8];
  #pragma unroll
  for (int i = 0; i < 8; ++i) {
    Ar0[i] = *(const bf16x8*)(pA0 + i * 32);
    Ar1[i] = *(const bf16x8*)(pA1 + i * 32);
  }

  f32x4 acc00{}, acc01{}, acc10{}, acc11{};
  bf16x8 cB0 = *(const bf16x8*)(pB0);
  bf16x8 cB1 = *(const bf16x8*)(pB1);
  #pragma unroll
  for (int it = 0; it < 8; ++it) {
    bf16x8 nB0, nB1;
    if (it < 7) {
      nB0 = *(const bf16x8*)(pB0 + (it + 1) * 32);
      nB1 = *(const bf16x8*)(pB1 + (it + 1) * 32);
    }
    acc00 = mfma_bf16(Ar0[it], cB0, acc00);
    acc01 = mfma_bf16(Ar0[it], cB1, acc01);
    acc10 = mfma_bf16(Ar1[it], cB0, acc10);
    acc11 = mfma_bf16(Ar1[it], cB1, acc11);
    if (it < 7) { cB0 = nB0; cB1 = nB1; }
  }

  float* zb = zpart + ((size_t)(kq * 64 + ms * 32 + kg * 4) << 12) + n0 + r;
  #pragma unroll
  for (int j = 0; j < 4; ++j) {
    zb[(size_t)j * NG]             = acc00[j];
    zb[(size_t)j * NG + 16]        = acc01[j];
    zb[(size_t)(16 + j) * NG]      = acc10[j];
    zb[(size_t)(16 + j) * NG + 16] = acc11[j];
  }
}

// ---------------- RNN epilogue (KQ=16) ----------------------------------
__global__ __launch_bounds__(256) void rnn_epi16_kernel(
    const float* __restrict__ zpart,
    const float* __restrict__ v, const float* __restrict__ Win,
    float* __restrict__ vv, float* __restrict__ zp,
    __hip_bfloat16* __restrict__ gs, int t) {
  const int g = blockIdx.x * 256 + threadIdx.x;
  const int b = g >> 10;
  const int n = (g & 1023) * 4;
  f32x4 s{};
  #pragma unroll
  for (int kq = 0; kq < 16; ++kq)
    s += *(const f32x4*)(zpart + ((size_t)(kq * 64 + b) << 12) + n);
  float2 vt = *(const float2*)(v + (b * T_STEPS + t) * 2);
  float4 wA = *(const float4*)(Win + 2 * n);
  float4 wB = *(const float4*)(Win + 2 * n + 4);
  f32x4 z;
  z[0] = s[0] + vt.x * wA.x + vt.y * wA.y;
  z[1] = s[1] + vt.x * wA.z + vt.y * wA.w;
  z[2] = s[2] + vt.x * wB.x + vt.y * wB.y;
  z[3] = s[3] + vt.x * wB.z + vt.y * wB.w;
  f32x4 vvo = *(const f32x4*)(vv + (size_t)b * NG + n);
  f32x4 zpo = *(const f32x4*)(zp + (size_t)b * NG + n);
  union { __hip_bfloat16 h[4]; uint2 u2; } o;
  f32x4 vvn;
  #pragma unroll
  for (int j = 0; j < 4; ++j) {
    z[j] -= 0.5f * vvo[j];                       // z uses OLD vv
    vvn[j] = fmaxf(vvo[j] + 0.1f * (zpo[j] - vvo[j]), 0.f);
    o.h[j] = __float2bfloat16(fmaxf(z[j], 0.f));
  }
  *(f32x4*)(vv + (size_t)b * NG + n) = vvn;
  *(f32x4*)(zp + (size_t)b * NG + n) = z;        // pre-relu z
  *(uint2*)(gs + (size_t)(b * T_STEPS + t) * NG + n) = o.u2;
}

// ---------------- RNN GEMM (round-4 verbatim, KQ=8 fallback) ------------
__global__ __launch_bounds__(256, 2) void rnn_gemm_kernel(
    const __hip_bfloat16* __restrict__ A, int strideA,
    const __hip_bfloat16* __restrict__ Wh,
    float* __restrict__ zpart) {
  const int lane = threadIdx.x & 63;
  const int w = threadIdx.x >> 6;
  const int ms = w >> 1, ns = w & 1;
  const int ng = blockIdx.x, kq = blockIdx.y;
  const int r = lane & 15;
  const int kg = lane >> 4;
  const int kbase = kq * 512 + kg * 8;
  const int n0 = ng * 64 + ns * 32;

  const __hip_bfloat16* pA0 = A + (size_t)(ms * 32 + r) * strideA + kbase;
  const __hip_bfloat16* pA1 = pA0 + (size_t)16 * strideA;
  const __hip_bfloat16* pB0 = Wh + (size_t)(n0 + r) * NG + kbase;
  const __hip_bfloat16* pB1 = pB0 + (size_t)16 * NG;

  f32x4 acc00{}, acc01{}, acc10{}, acc11{};
  bf16x8 cA0 = *(const bf16x8*)(pA0);
  bf16x8 cA1 = *(const bf16x8*)(pA1);
  bf16x8 cB0 = *(const bf16x8*)(pB0);
  bf16x8 cB1 = *(const bf16x8*)(pB1);
  #pragma unroll
  for (int it = 0; it < 16; ++it) {
    bf16x8 nA0, nA1, nB0, nB1;
    if (it < 15) {
      nA0 = *(const bf16x8*)(pA0 + (it + 1) * 32);
      nA1 = *(const bf16x8*)(pA1 + (it + 1) * 32);
      nB0 = *(const bf16x8*)(pB0 + (it + 1) * 32);
      nB1 = *(const bf16x8*)(pB1 + (it + 1) * 32);
    }
    acc00 = mfma_bf16(cA0, cB0, acc00);
    acc01 = mfma_bf16(cA0, cB1, acc01);
    acc10 = mfma_bf16(cA1, cB0, acc10);
    acc11 = mfma_bf16(cA1, cB1, acc11);
    if (it < 15) { cA0 = nA0; cA1 = nA1; cB0 = nB0; cB1 = nB1; }
  }

  float* zb = zpart + ((size_t)(kq * 64 + ms * 32 + kg * 4) << 12) + n0 + r;
  #pragma unroll
  for (int j = 0; j < 4; ++j) {
    zb[(size_t)j * NG]             = acc00[j];
    zb[(size_t)j * NG + 16]        = acc01[j];
    zb[(size_t)(16 + j) * NG]      = acc10[j];
    zb[(size_t)(16 + j) * NG + 16] = acc11[j];
  }
}

// ---------------- RNN epilogue (KQ=8 fallback) --------------------------
__global__ __launch_bounds__(256) void rnn_epi_kernel(
    const float* __restrict__ zpart,
    const float* __restrict__ v, const float* __restrict__ Win,
    float* __restrict__ vv, float* __restrict__ zp,
    __hip_bfloat16* __restrict__ gs, int t) {
  const int g = blockIdx.x * 256 + threadIdx.x;
  const int b = g >> 10;
  const int n = (g & 1023) * 4;
  f32x4 s{};
  #pragma unroll
  for (int kq = 0; kq < 8; ++kq)
    s += *(const f32x4*)(zpart + ((size_t)(kq * 64 + b) << 12) + n);
  float2 vt = *(const float2*)(v + (b * T_STEPS + t) * 2);
  float4 wA = *(const float4*)(Win + 2 * n);
  float4 wB = *(const float4*)(Win + 2 * n + 4);
  f32x4 z;
  z[0] = s[0] + vt.x * wA.x + vt.y * wA.y;
  z[1] = s[1] + vt.x * wA.z + vt.y * wA.w;
  z[2] = s[2] + vt.x * wB.x + vt.y * wB.y;
  z[3] = s[3] + vt.x * wB.z + vt.y * wB.w;
  f32x4 vvo = *(const f32x4*)(vv + (size_t)b * NG + n);
  f32x4 zpo = *(const f32x4*)(zp + (size_t)b * NG + n);
  union { __hip_bfloat16 h[4]; uint2 u2; } o;
  f32x4 vvn;
  #pragma unroll
  for (int j = 0; j < 4; ++j) {
    z[j] -= 0.5f * vvo[j];
    vvn[j] = fmaxf(vvo[j] + 0.1f * (zpo[j] - vvo[j]), 0.f);
    o.h[j] = __float2bfloat16(fmaxf(z[j], 0.f));
  }
  *(f32x4*)(vv + (size_t)b * NG + n) = vvn;
  *(f32x4*)(zp + (size_t)b * NG + n) = z;
  *(uint2*)(gs + (size_t)(b * T_STEPS + t) * NG + n) = o.u2;
}

// ---------------- decoder: logits = gs @ W_dec^T (round-8 verbatim) -----
__global__ __launch_bounds__(256) void decoder_kernel(
    const __hip_bfloat16* __restrict__ gs,
    const __hip_bfloat16* __restrict__ Wd,
    float* __restrict__ out) {
  __shared__ float sred[3][16][128];
  const int tid = threadIdx.x;
  const int lane = tid & 63;
  const int kh = tid >> 6;
  const int m0 = blockIdx.x * 16;
  const int n0 = blockIdx.y * 128;
  const int r = lane & 15;
  const int kg = lane >> 4;

  const __hip_bfloat16* pA = gs + (size_t)(m0 + r) * NG + kh * 1024 + kg * 8;
  const __hip_bfloat16* pB[8];
  #pragma unroll
  for (int i = 0; i < 8; ++i)
    pB[i] = Wd + (size_t)(n0 + i * 16 + r) * NG + kh * 1024 + kg * 8;

  f32x4 acc[8] = {};
  bf16x8 A0, A1, B0[8], B1[8];
  A0 = *(const bf16x8*)(pA);
  A1 = *(const bf16x8*)(pA + 32);
  #pragma unroll
  for (int i = 0; i < 8; ++i) {
    B0[i] = *(const bf16x8*)(pB[i]);
    B1[i] = *(const bf16x8*)(pB[i] + 32);
  }
  for (int c = 0; c < 32; c += 2) {
    {
      bf16x8 a = A0;
      bf16x8 bcur[8];
      #pragma unroll
      for (int i = 0; i < 8; ++i) bcur[i] = B0[i];
      if (c + 2 < 32) {
        A0 = *(const bf16x8*)(pA + (c + 2) * 32);
        #pragma unroll
        for (int i = 0; i < 8; ++i) B0[i] = *(const bf16x8*)(pB[i] + (c + 2) * 32);
      }
      #pragma unroll
      for (int i = 0; i < 8; ++i) acc[i] = mfma_bf16(a, bcur[i], acc[i]);
    }
    {
      bf16x8 a = A1;
      bf16x8 bcur[8];
      #pragma unroll
      for (int i = 0; i < 8; ++i) bcur[i] = B1[i];
      if (c + 3 < 32) {
        A1 = *(const bf16x8*)(pA + (c + 3) * 32);
        #pragma unroll
        for (int i = 0; i < 8; ++i) B1[i] = *(const bf16x8*)(pB[i] + (c + 3) * 32);
      }
      #pragma unroll
      for (int i = 0; i < 8; ++i) acc[i] = mfma_bf16(a, bcur[i], acc[i]);
    }
  }

  if (kh > 0) {
    #pragma unroll
    for (int j = 0; j < 4; ++j)
      #pragma unroll
      for (int i = 0; i < 8; ++i)
        sred[kh - 1][kg * 4 + j][i * 16 + r] = acc[i][j];
  }
  __syncthreads();
  if (kh == 0) {
    #pragma unroll
    for (int j = 0; j < 4; ++j) {
      const int row = kg * 4 + j;
      float* po = out + (size_t)(m0 + row) * NP + n0;
      #pragma unroll
      for (int i = 0; i < 8; ++i) {
        const int col = i * 16 + r;
        po[col] = acc[i][j] + sred[0][row][col] + sred[1][row][col]
                            + sred[2][row][col];
      }
    }
  }
}

// ---------------- log_softmax over rows of 512 (in place) ---------------
__global__ __launch_bounds__(256) void logsoftmax_kernel(float* __restrict__ out) {
  float* row = out + (size_t)blockIdx.x * NP;
  const int tid = threadIdx.x;
  const int lane = tid & 63, wid = tid >> 6;
  float x0 = row[tid], x1 = row[tid + 256];
  float m = fmaxf(x0, x1);
  #pragma unroll
  for (int off = 32; off >= 1; off >>= 1) m = fmaxf(m, __shfl_xor(m, off));
  __shared__ float sred[8];
  if (lane == 0) sred[wid] = m;
  __syncthreads();
  m = fmaxf(fmaxf(sred[0], sred[1]), fmaxf(sred[2], sred[3]));
  float e = __expf(x0 - m) + __expf(x1 - m);
  #pragma unroll
  for (int off = 32; off >= 1; off >>= 1) e += __shfl_xor(e, off);
  if (lane == 0) sred[4 + wid] = e;
  __syncthreads();
  float lse = m + __logf(sred[4] + sred[5] + sred[6] + sred[7]);
  row[tid] = x0 - lse;
  row[tid + 256] = x1 - lse;
}

extern "C" void kernel_launch(void* const* d_in, const int* in_sizes, int n_in,
                              void* d_out, int out_size, void* d_ws, size_t ws_size,
                              hipStream_t stream) {
  const float* v    = (const float*)d_in[0];  // [64,100,2]
  const float* p0   = (const float*)d_in[1];  // [64,512]
  const float* Wenc = (const float*)d_in[2];  // [4096,512]
  const float* Win  = (const float*)d_in[3];  // [4096,2]
  const float* Wh   = (const float*)d_in[4];  // [4096,4096]
  const float* Wdec = (const float*)d_in[5];  // [512,4096]
  float* out = (float*)d_out;                 // [64,100,512]

  char* ws = (char*)d_ws;
  __hip_bfloat16* gs    = (__hip_bfloat16*)(ws);               // 52,428,800
  __hip_bfloat16* Wh_bf = (__hip_bfloat16*)(ws + 52428800);    // 33,554,432
  float*          zpart = (float*)(ws + 85983232);             // 8 or 16.8 MB
  __hip_bfloat16* Wdec_bf = (__hip_bfloat16*)(ws + 85983232);  // aliases zpart

  const bool big = ws_size >= 105381888ull;   // room for KQ=16 zpart?
  const size_t tail = big ? 102760448ull : 94371840ull;
  float*          vv    = (float*)(ws + tail);
  float*          zp    = (float*)(ws + tail + 1048576);
  __hip_bfloat16* h0_bf = (__hip_bfloat16*)(ws + tail + 2097152);

  hipMemsetAsync(vv, 0, 2 * 1048576, stream);   // vv + zp (contiguous)
  cvt_bf16_kernel<<<8192, 256, 0, stream>>>(Wh, Wh_bf, 2097152);
  encoder_kernel<<<256, 256, 0, stream>>>(p0, Wenc, h0_bf);

  if (big) {
    for (int t = 0; t < T_STEPS; ++t) {
      const __hip_bfloat16* A = (t == 0) ? h0_bf : (gs + (size_t)(t - 1) * NG);
      int sA = (t == 0) ? NG : T_STEPS * NG;
      rnn_gemm16_kernel<<<dim3(64, 16), 256, 0, stream>>>(A, sA, Wh_bf, zpart);
      rnn_epi16_kernel<<<256, 256, 0, stream>>>(zpart, v, Win, vv, zp, gs, t);
    }
  } else {
    for (int t = 0; t < T_STEPS; ++t) {
      const __hip_bfloat16* A = (t == 0) ? h0_bf : (gs + (size_t)(t - 1) * NG);
      int sA = (t == 0) ? NG : T_STEPS * NG;
      rnn_gemm_kernel<<<dim3(64, 8), 256, 0, stream>>>(A, sA, Wh_bf, zpart);
      rnn_epi_kernel<<<256, 256, 0, stream>>>(zpart, v, Win, vv, zp, gs, t);
    }
  }

  cvt_bf16_kernel<<<1024, 256, 0, stream>>>(Wdec, Wdec_bf, 262144);  // after RNN
  decoder_kernel<<<dim3(400, 4), 256, 0, stream>>>(gs, Wdec_bf, out);
  logsoftmax_kernel<<<6400, 256, 0, stream>>>(out);
}

// Round 10
// 2326.743 us; speedup vs baseline: 1.0925x; 1.0925x over previous
//
#include <hip/hip_runtime.h>
#include <hip/hip_bf16.h>

#define T_STEPS 100
#define NG 4096
#define NP 512

typedef __bf16 bf16x8 __attribute__((ext_vector_type(8)));
typedef float f32x4 __attribute__((ext_vector_type(4)));

__device__ __forceinline__ f32x4 mfma_bf16(bf16x8 a, bf16x8 b, f32x4 c) {
  return __builtin_amdgcn_mfma_f32_16x16x32_bf16(a, b, c, 0, 0, 0);
}

// ---------------- f32 -> bf16 conversion, 8 elems/thread ----------------
__global__ __launch_bounds__(256) void cvt_bf16_kernel(const float* __restrict__ in,
                                                       __hip_bfloat16* __restrict__ out,
                                                       int n8) {
  int i = blockIdx.x * 256 + threadIdx.x;
  if (i >= n8) return;
  const float4* p = reinterpret_cast<const float4*>(in) + (size_t)i * 2;
  float4 f0 = p[0], f1 = p[1];
  union { __hip_bfloat16 h[8]; uint4 u; } z;
  z.h[0] = __float2bfloat16(f0.x); z.h[1] = __float2bfloat16(f0.y);
  z.h[2] = __float2bfloat16(f0.z); z.h[3] = __float2bfloat16(f0.w);
  z.h[4] = __float2bfloat16(f1.x); z.h[5] = __float2bfloat16(f1.y);
  z.h[6] = __float2bfloat16(f1.z); z.h[7] = __float2bfloat16(f1.w);
  *(reinterpret_cast<uint4*>(out) + i) = z.u;
}

// ---------------- encoder: h0 = p0 @ W_enc^T  -> bf16 -------------------
__global__ __launch_bounds__(256) void encoder_kernel(const float* __restrict__ p0,
                                                      const float* __restrict__ Wenc,
                                                      __hip_bfloat16* __restrict__ h0) {
  __shared__ float sp[64 * 129];
  const int tid = threadIdx.x;
  const int nb = blockIdx.x * 16;
  const int b = tid & 63;
  const int jg = tid >> 6;
  float acc[4] = {0.f, 0.f, 0.f, 0.f};
  for (int kc = 0; kc < NP; kc += 128) {
    __syncthreads();
    #pragma unroll
    for (int i = 0; i < 32; ++i) {
      int e = tid + i * 256;
      int bb = e >> 7, kk = e & 127;
      sp[bb * 129 + kk] = p0[bb * NP + kc + kk];
    }
    __syncthreads();
    for (int kk = 0; kk < 128; ++kk) {
      float pv = sp[b * 129 + kk];
      #pragma unroll
      for (int jj = 0; jj < 4; ++jj)
        acc[jj] += pv * Wenc[(size_t)(nb + jg * 4 + jj) * NP + kc + kk];
    }
  }
  #pragma unroll
  for (int jj = 0; jj < 4; ++jj)
    h0[(size_t)b * NG + nb + jg * 4 + jj] = __float2bfloat16(acc[jj]);
}

// ---------------- RNN GEMM partial: zpart[kq] = A_kslice @ Wh_kslice^T --
// grid (8 kq, 64 ng) -- kq FASTEST so XCD = linear%8 = kq:
//   * each XCD reads only its own 64 KB A-slice (one L3 miss, then L2 hits
//     for the other 63 blocks) instead of all 512 KB (r8 was ng%8),
//   * zpart[kq] writes stay in XCD kq's L2,
//   * Wh k-slice x all-n (4.2 MB) ~L2-resident per XCD across launches.
// Block 256 = 4 waves (ms = w>>1: 32 b-rows; ns = w&1: 32 n-cols).
// Wave 32b x 32n x 512k, 2x2 frags = 4 indep MFMA chains.
// Pipelining: A 4-deep / B 2-deep statically-indexed rings (full unroll
// => all indices compile-time, stays in VGPRs): 6 A + 4 B loads in flight.
__global__ __launch_bounds__(256, 2) void rnn_gemm_kernel(
    const __hip_bfloat16* __restrict__ A, int strideA,
    const __hip_bfloat16* __restrict__ Wh,
    float* __restrict__ zpart) {
  const int lane = threadIdx.x & 63;
  const int w = threadIdx.x >> 6;
  const int ms = w >> 1, ns = w & 1;
  const int kq = blockIdx.x, ng = blockIdx.y;   // kq fastest -> XCD = kq
  const int r = lane & 15;
  const int kg = lane >> 4;
  const int kbase = kq * 512 + kg * 8;
  const int n0 = ng * 64 + ns * 32;

  const __hip_bfloat16* pA0 = A + (size_t)(ms * 32 + r) * strideA + kbase;
  const __hip_bfloat16* pA1 = pA0 + (size_t)16 * strideA;
  const __hip_bfloat16* pB0 = Wh + (size_t)(n0 + r) * NG + kbase;
  const __hip_bfloat16* pB1 = pB0 + (size_t)16 * NG;

  bf16x8 A0b[4], A1b[4], B0b[2], B1b[2];
  #pragma unroll
  for (int i = 0; i < 4; ++i) {
    A0b[i] = *(const bf16x8*)(pA0 + i * 32);
    A1b[i] = *(const bf16x8*)(pA1 + i * 32);
  }
  #pragma unroll
  for (int i = 0; i < 2; ++i) {
    B0b[i] = *(const bf16x8*)(pB0 + i * 32);
    B1b[i] = *(const bf16x8*)(pB1 + i * 32);
  }

  f32x4 acc00{}, acc01{}, acc10{}, acc11{};
  #pragma unroll
  for (int it = 0; it < 16; ++it) {
    const int sa = it & 3, sb = it & 1;   // compile-time after unroll
    bf16x8 a0 = A0b[sa], a1 = A1b[sa], b0 = B0b[sb], b1 = B1b[sb];
    if (it < 12) {
      A0b[sa] = *(const bf16x8*)(pA0 + (it + 4) * 32);
      A1b[sa] = *(const bf16x8*)(pA1 + (it + 4) * 32);
    }
    if (it < 14) {
      B0b[sb] = *(const bf16x8*)(pB0 + (it + 2) * 32);
      B1b[sb] = *(const bf16x8*)(pB1 + (it + 2) * 32);
    }
    acc00 = mfma_bf16(a0, b0, acc00);
    acc01 = mfma_bf16(a0, b1, acc01);
    acc10 = mfma_bf16(a1, b0, acc10);
    acc11 = mfma_bf16(a1, b1, acc11);
  }

  // store: C row b = ms*32 + fi*16 + kg*4 + j; col n = n0 + fj*16 + r
  float* zb = zpart + ((size_t)(kq * 64 + ms * 32 + kg * 4) << 12) + n0 + r;
  #pragma unroll
  for (int j = 0; j < 4; ++j) {
    zb[(size_t)j * NG]             = acc00[j];
    zb[(size_t)j * NG + 16]        = acc01[j];
    zb[(size_t)(16 + j) * NG]      = acc10[j];
    zb[(size_t)(16 + j) * NG + 16] = acc11[j];
  }
}

// ---------------- RNN epilogue: sum partials + recurrence + relu --------
// grid 256 x 256 thr; thread handles 4 consecutive n of one b.
__global__ __launch_bounds__(256) void rnn_epi_kernel(
    const float* __restrict__ zpart,
    const float* __restrict__ v, const float* __restrict__ Win,
    float* __restrict__ vv, float* __restrict__ zp,
    __hip_bfloat16* __restrict__ gs, int t) {
  const int g = blockIdx.x * 256 + threadIdx.x;   // 0..65535
  const int b = g >> 10;
  const int n = (g & 1023) * 4;
  f32x4 s{};
  #pragma unroll
  for (int kq = 0; kq < 8; ++kq)
    s += *(const f32x4*)(zpart + ((size_t)(kq * 64 + b) << 12) + n);
  float2 vt = *(const float2*)(v + (b * T_STEPS + t) * 2);
  float4 wA = *(const float4*)(Win + 2 * n);
  float4 wB = *(const float4*)(Win + 2 * n + 4);
  f32x4 z;
  z[0] = s[0] + vt.x * wA.x + vt.y * wA.y;
  z[1] = s[1] + vt.x * wA.z + vt.y * wA.w;
  z[2] = s[2] + vt.x * wB.x + vt.y * wB.y;
  z[3] = s[3] + vt.x * wB.z + vt.y * wB.w;
  f32x4 vvo = *(const f32x4*)(vv + (size_t)b * NG + n);
  f32x4 zpo = *(const f32x4*)(zp + (size_t)b * NG + n);
  union { __hip_bfloat16 h[4]; uint2 u2; } o;
  f32x4 vvn;
  #pragma unroll
  for (int j = 0; j < 4; ++j) {
    z[j] -= 0.5f * vvo[j];                       // z uses OLD vv
    vvn[j] = fmaxf(vvo[j] + 0.1f * (zpo[j] - vvo[j]), 0.f);
    o.h[j] = __float2bfloat16(fmaxf(z[j], 0.f));
  }
  *(f32x4*)(vv + (size_t)b * NG + n) = vvn;
  *(f32x4*)(zp + (size_t)b * NG + n) = z;        // pre-relu z
  *(uint2*)(gs + (size_t)(b * T_STEPS + t) * NG + n) = o.u2;
}

// ---------------- decoder: logits = gs @ W_dec^T (round-8 verbatim) -----
__global__ __launch_bounds__(256) void decoder_kernel(
    const __hip_bfloat16* __restrict__ gs,
    const __hip_bfloat16* __restrict__ Wd,
    float* __restrict__ out) {
  __shared__ float sred[3][16][128];
  const int tid = threadIdx.x;
  const int lane = tid & 63;
  const int kh = tid >> 6;
  const int m0 = blockIdx.x * 16;
  const int n0 = blockIdx.y * 128;
  const int r = lane & 15;
  const int kg = lane >> 4;

  const __hip_bfloat16* pA = gs + (size_t)(m0 + r) * NG + kh * 1024 + kg * 8;
  const __hip_bfloat16* pB[8];
  #pragma unroll
  for (int i = 0; i < 8; ++i)
    pB[i] = Wd + (size_t)(n0 + i * 16 + r) * NG + kh * 1024 + kg * 8;

  f32x4 acc[8] = {};
  bf16x8 A0, A1, B0[8], B1[8];
  A0 = *(const bf16x8*)(pA);
  A1 = *(const bf16x8*)(pA + 32);
  #pragma unroll
  for (int i = 0; i < 8; ++i) {
    B0[i] = *(const bf16x8*)(pB[i]);
    B1[i] = *(const bf16x8*)(pB[i] + 32);
  }
  for (int c = 0; c < 32; c += 2) {
    {
      bf16x8 a = A0;
      bf16x8 bcur[8];
      #pragma unroll
      for (int i = 0; i < 8; ++i) bcur[i] = B0[i];
      if (c + 2 < 32) {
        A0 = *(const bf16x8*)(pA + (c + 2) * 32);
        #pragma unroll
        for (int i = 0; i < 8; ++i) B0[i] = *(const bf16x8*)(pB[i] + (c + 2) * 32);
      }
      #pragma unroll
      for (int i = 0; i < 8; ++i) acc[i] = mfma_bf16(a, bcur[i], acc[i]);
    }
    {
      bf16x8 a = A1;
      bf16x8 bcur[8];
      #pragma unroll
      for (int i = 0; i < 8; ++i) bcur[i] = B1[i];
      if (c + 3 < 32) {
        A1 = *(const bf16x8*)(pA + (c + 3) * 32);
        #pragma unroll
        for (int i = 0; i < 8; ++i) B1[i] = *(const bf16x8*)(pB[i] + (c + 3) * 32);
      }
      #pragma unroll
      for (int i = 0; i < 8; ++i) acc[i] = mfma_bf16(a, bcur[i], acc[i]);
    }
  }

  if (kh > 0) {
    #pragma unroll
    for (int j = 0; j < 4; ++j)
      #pragma unroll
      for (int i = 0; i < 8; ++i)
        sred[kh - 1][kg * 4 + j][i * 16 + r] = acc[i][j];
  }
  __syncthreads();
  if (kh == 0) {
    #pragma unroll
    for (int j = 0; j < 4; ++j) {
      const int row = kg * 4 + j;
      float* po = out + (size_t)(m0 + row) * NP + n0;
      #pragma unroll
      for (int i = 0; i < 8; ++i) {
        const int col = i * 16 + r;
        po[col] = acc[i][j] + sred[0][row][col] + sred[1][row][col]
                            + sred[2][row][col];
      }
    }
  }
}

// ---------------- log_softmax over rows of 512 (in place) ---------------
__global__ __launch_bounds__(256) void logsoftmax_kernel(float* __restrict__ out) {
  float* row = out + (size_t)blockIdx.x * NP;
  const int tid = threadIdx.x;
  const int lane = tid & 63, wid = tid >> 6;
  float x0 = row[tid], x1 = row[tid + 256];
  float m = fmaxf(x0, x1);
  #pragma unroll
  for (int off = 32; off >= 1; off >>= 1) m = fmaxf(m, __shfl_xor(m, off));
  __shared__ float sred[8];
  if (lane == 0) sred[wid] = m;
  __syncthreads();
  m = fmaxf(fmaxf(sred[0], sred[1]), fmaxf(sred[2], sred[3]));
  float e = __expf(x0 - m) + __expf(x1 - m);
  #pragma unroll
  for (int off = 32; off >= 1; off >>= 1) e += __shfl_xor(e, off);
  if (lane == 0) sred[4 + wid] = e;
  __syncthreads();
  float lse = m + __logf(sred[4] + sred[5] + sred[6] + sred[7]);
  row[tid] = x0 - lse;
  row[tid + 256] = x1 - lse;
}

extern "C" void kernel_launch(void* const* d_in, const int* in_sizes, int n_in,
                              void* d_out, int out_size, void* d_ws, size_t ws_size,
                              hipStream_t stream) {
  const float* v    = (const float*)d_in[0];  // [64,100,2]
  const float* p0   = (const float*)d_in[1];  // [64,512]
  const float* Wenc = (const float*)d_in[2];  // [4096,512]
  const float* Win  = (const float*)d_in[3];  // [4096,2]
  const float* Wh   = (const float*)d_in[4];  // [4096,4096]
  const float* Wdec = (const float*)d_in[5];  // [512,4096]
  float* out = (float*)d_out;                 // [64,100,512]

  char* ws = (char*)d_ws;
  __hip_bfloat16* gs      = (__hip_bfloat16*)(ws);               // 52,428,800
  __hip_bfloat16* Wh_bf   = (__hip_bfloat16*)(ws + 52428800);    // 33,554,432
  float*          zpart   = (float*)(ws + 85983232);             //  8,388,608
  __hip_bfloat16* Wdec_bf = (__hip_bfloat16*)(ws + 85983232);    // aliases zpart (used after RNN)
  float*          vv      = (float*)(ws + 94371840);             //  1,048,576
  float*          zp      = (float*)(ws + 95420416);             //  1,048,576
  __hip_bfloat16* h0_bf   = (__hip_bfloat16*)(ws + 96468992);    //    524,288
  // total 96,993,280 B

  hipMemsetAsync(vv, 0, 2 * 1048576, stream);   // vv + zp (contiguous)
  cvt_bf16_kernel<<<8192, 256, 0, stream>>>(Wh, Wh_bf, 2097152);
  encoder_kernel<<<256, 256, 0, stream>>>(p0, Wenc, h0_bf);

  for (int t = 0; t < T_STEPS; ++t) {
    const __hip_bfloat16* A = (t == 0) ? h0_bf : (gs + (size_t)(t - 1) * NG);
    int sA = (t == 0) ? NG : T_STEPS * NG;
    rnn_gemm_kernel<<<dim3(8, 64), 256, 0, stream>>>(A, sA, Wh_bf, zpart);
    rnn_epi_kernel<<<256, 256, 0, stream>>>(zpart, v, Win, vv, zp, gs, t);
  }

  cvt_bf16_kernel<<<1024, 256, 0, stream>>>(Wdec, Wdec_bf, 262144);  // after RNN (aliases zpart)
  decoder_kernel<<<dim3(400, 4), 256, 0, stream>>>(gs, Wdec_bf, out);
  logsoftmax_kernel<<<6400, 256, 0, stream>>>(out);
}

// Round 11
// 1420.221 us; speedup vs baseline: 1.7899x; 1.6383x over previous
//
#include <hip/hip_runtime.h>
#include <hip/hip_bf16.h>

#define T_STEPS 100
#define NG 4096
#define NP 512

typedef __bf16 bf16x8 __attribute__((ext_vector_type(8)));
typedef float f32x4 __attribute__((ext_vector_type(4)));

__device__ __forceinline__ f32x4 mfma_bf16(bf16x8 a, bf16x8 b, f32x4 c) {
  return __builtin_amdgcn_mfma_f32_16x16x32_bf16(a, b, c, 0, 0, 0);
}

// async global->LDS, 16B per lane; LDS dest = wave-uniform base + lane*16
__device__ __forceinline__ void gload16(const void* g, void* l) {
  __builtin_amdgcn_global_load_lds(
      (const __attribute__((address_space(1))) void*)g,
      (__attribute__((address_space(3))) void*)l, 16, 0, 0);
}

// ---------------- f32 -> bf16 conversion, 8 elems/thread ----------------
__global__ __launch_bounds__(256) void cvt_bf16_kernel(const float* __restrict__ in,
                                                       __hip_bfloat16* __restrict__ out,
                                                       int n8) {
  int i = blockIdx.x * 256 + threadIdx.x;
  if (i >= n8) return;
  const float4* p = reinterpret_cast<const float4*>(in) + (size_t)i * 2;
  float4 f0 = p[0], f1 = p[1];
  union { __hip_bfloat16 h[8]; uint4 u; } z;
  z.h[0] = __float2bfloat16(f0.x); z.h[1] = __float2bfloat16(f0.y);
  z.h[2] = __float2bfloat16(f0.z); z.h[3] = __float2bfloat16(f0.w);
  z.h[4] = __float2bfloat16(f1.x); z.h[5] = __float2bfloat16(f1.y);
  z.h[6] = __float2bfloat16(f1.z); z.h[7] = __float2bfloat16(f1.w);
  *(reinterpret_cast<uint4*>(out) + i) = z.u;
}

// ---------------- encoder: h0 = p0 @ W_enc^T  -> bf16 -------------------
__global__ __launch_bounds__(256) void encoder_kernel(const float* __restrict__ p0,
                                                      const float* __restrict__ Wenc,
                                                      __hip_bfloat16* __restrict__ h0) {
  __shared__ float sp[64 * 129];
  const int tid = threadIdx.x;
  const int nb = blockIdx.x * 16;
  const int b = tid & 63;
  const int jg = tid >> 6;
  float acc[4] = {0.f, 0.f, 0.f, 0.f};
  for (int kc = 0; kc < NP; kc += 128) {
    __syncthreads();
    #pragma unroll
    for (int i = 0; i < 32; ++i) {
      int e = tid + i * 256;
      int bb = e >> 7, kk = e & 127;
      sp[bb * 129 + kk] = p0[bb * NP + kc + kk];
    }
    __syncthreads();
    for (int kk = 0; kk < 128; ++kk) {
      float pv = sp[b * 129 + kk];
      #pragma unroll
      for (int jj = 0; jj < 4; ++jj)
        acc[jj] += pv * Wenc[(size_t)(nb + jg * 4 + jj) * NP + kc + kk];
    }
  }
  #pragma unroll
  for (int jj = 0; jj < 4; ++jj)
    h0[(size_t)b * NG + nb + jg * 4 + jj] = __float2bfloat16(acc[jj]);
}

// ---------------- RNN GEMM partial, LDS-staged (m97-style) --------------
// grid (8 kq, 64 ng) -- kq fastest => XCD = kq (A slice + zpart L2-local).
// Block 256 = 4 waves (ms = w>>1: 32 b-rows; ns = w&1: 32 n-cols), tile
// 64b x 64n x 512k, BK=128 -> 4 k-iters, double-buffered 64 KB LDS.
// Staging: global_load_lds width=16, LDS dest linear, global source
// pre-swizzled with byte ^= ((row&7)<<4); ds_read applies the same XOR
// (involution both sides -- pattern proven in round 3). k-accumulation
// order identical to the r4 kernel => zpart bitwise identical.
__global__ __launch_bounds__(256, 2) void rnn_gemm_kernel(
    const __hip_bfloat16* __restrict__ A, int strideA,
    const __hip_bfloat16* __restrict__ Wh,
    float* __restrict__ zpart) {
  __shared__ char smem[65536];   // [2 dbuf][A 16KB | B 16KB]
  const int tid = threadIdx.x;
  const int lane = tid & 63;
  const int w = tid >> 6;
  const int ms = w >> 1, ns = w & 1;
  const int kq = blockIdx.x, ng = blockIdx.y;
  const int r = lane & 15;
  const int kg = lane >> 4;
  const int n0 = ng * 64;

  const __hip_bfloat16* gA = A + (size_t)kq * 512;             // + row*strideA + it*128
  const __hip_bfloat16* gB = Wh + (size_t)n0 * NG + (size_t)kq * 512;

  // fragment read offsets (XOR swizzle folded per-lane; row&7 == r&7)
  const int xsw = (kg ^ (r & 3)) << 4;
  const int xA0 = (ms * 32 + r) * 256 + xsw;
  const int xA1 = xA0 + 16 * 256;
  const int xB0 = (ns * 32 + r) * 256 + xsw;
  const int xB1 = xB0 + 16 * 256;
  const int x6 = (r & 4) << 4;
  const int ksX[4] = {0 ^ x6, 64 ^ x6, 128 ^ x6, 192 ^ x6};

  // stage one 64x128 bf16 tile (16KB): 4 calls x 4KB; chunk c = i*256+tid,
  // dest byte = c*16 = row*256 + colB; src col byte = colB ^ ((row&7)<<4)
  auto stageA = [&](int buf, int it) {
    #pragma unroll
    for (int i = 0; i < 4; ++i) {
      int c = i * 256 + tid;
      int row = c >> 4;
      int colB = (c & 15) * 16;
      int srcB = colB ^ ((row & 7) << 4);
      const char* src = (const char*)(gA + (size_t)row * strideA + it * 128) + srcB;
      gload16(src, smem + buf * 32768 + i * 4096 + w * 1024);
    }
  };
  auto stageB = [&](int buf, int it) {
    #pragma unroll
    for (int i = 0; i < 4; ++i) {
      int c = i * 256 + tid;
      int row = c >> 4;
      int colB = (c & 15) * 16;
      int srcB = colB ^ ((row & 7) << 4);
      const char* src = (const char*)(gB + (size_t)row * NG + it * 128) + srcB;
      gload16(src, smem + buf * 32768 + 16384 + i * 4096 + w * 1024);
    }
  };

  stageA(0, 0);
  stageB(0, 0);
  asm volatile("s_waitcnt vmcnt(0)" ::: "memory");
  __syncthreads();

  f32x4 acc00{}, acc01{}, acc10{}, acc11{};
  #pragma unroll
  for (int it = 0; it < 4; ++it) {
    const int buf = it & 1;
    if (it < 3) { stageA(buf ^ 1, it + 1); stageB(buf ^ 1, it + 1); }
    const char* bA = smem + buf * 32768;
    const char* bB = bA + 16384;
    #pragma unroll
    for (int ks = 0; ks < 4; ++ks) {           // k = it*128 + ks*32 (ascending, == r4 order)
      bf16x8 a0 = *(const bf16x8*)(bA + xA0 + ksX[ks]);
      bf16x8 a1 = *(const bf16x8*)(bA + xA1 + ksX[ks]);
      bf16x8 b0 = *(const bf16x8*)(bB + xB0 + ksX[ks]);
      bf16x8 b1 = *(const bf16x8*)(bB + xB1 + ksX[ks]);
      acc00 = mfma_bf16(a0, b0, acc00);
      acc01 = mfma_bf16(a0, b1, acc01);
      acc10 = mfma_bf16(a1, b0, acc10);
      acc11 = mfma_bf16(a1, b1, acc11);
    }
    asm volatile("s_waitcnt vmcnt(0)" ::: "memory");
    __syncthreads();
  }

  // store: C row b = ms*32 + fi*16 + kg*4 + j; col n = n0 + ns*32 + fj*16 + r
  float* zb = zpart + ((size_t)(kq * 64 + ms * 32 + kg * 4) << 12) + n0 + ns * 32 + r;
  #pragma unroll
  for (int j = 0; j < 4; ++j) {
    zb[(size_t)j * NG]             = acc00[j];
    zb[(size_t)j * NG + 16]        = acc01[j];
    zb[(size_t)(16 + j) * NG]      = acc10[j];
    zb[(size_t)(16 + j) * NG + 16] = acc11[j];
  }
}

// ---------------- RNN epilogue: sum partials + recurrence + relu --------
__global__ __launch_bounds__(256) void rnn_epi_kernel(
    const float* __restrict__ zpart,
    const float* __restrict__ v, const float* __restrict__ Win,
    float* __restrict__ vv, float* __restrict__ zp,
    __hip_bfloat16* __restrict__ gs, int t) {
  const int g = blockIdx.x * 256 + threadIdx.x;   // 0..65535
  const int b = g >> 10;
  const int n = (g & 1023) * 4;
  f32x4 s{};
  #pragma unroll
  for (int kq = 0; kq < 8; ++kq)
    s += *(const f32x4*)(zpart + ((size_t)(kq * 64 + b) << 12) + n);
  float2 vt = *(const float2*)(v + (b * T_STEPS + t) * 2);
  float4 wA = *(const float4*)(Win + 2 * n);
  float4 wB = *(const float4*)(Win + 2 * n + 4);
  f32x4 z;
  z[0] = s[0] + vt.x * wA.x + vt.y * wA.y;
  z[1] = s[1] + vt.x * wA.z + vt.y * wA.w;
  z[2] = s[2] + vt.x * wB.x + vt.y * wB.y;
  z[3] = s[3] + vt.x * wB.z + vt.y * wB.w;
  f32x4 vvo = *(const f32x4*)(vv + (size_t)b * NG + n);
  f32x4 zpo = *(const f32x4*)(zp + (size_t)b * NG + n);
  union { __hip_bfloat16 h[4]; uint2 u2; } o;
  f32x4 vvn;
  #pragma unroll
  for (int j = 0; j < 4; ++j) {
    z[j] -= 0.5f * vvo[j];                       // z uses OLD vv
    vvn[j] = fmaxf(vvo[j] + 0.1f * (zpo[j] - vvo[j]), 0.f);
    o.h[j] = __float2bfloat16(fmaxf(z[j], 0.f));
  }
  *(f32x4*)(vv + (size_t)b * NG + n) = vvn;
  *(f32x4*)(zp + (size_t)b * NG + n) = z;        // pre-relu z
  *(uint2*)(gs + (size_t)(b * T_STEPS + t) * NG + n) = o.u2;
}

// ---------------- decoder: logits = gs @ W_dec^T (round-8 verbatim) -----
__global__ __launch_bounds__(256) void decoder_kernel(
    const __hip_bfloat16* __restrict__ gs,
    const __hip_bfloat16* __restrict__ Wd,
    float* __restrict__ out) {
  __shared__ float sred[3][16][128];
  const int tid = threadIdx.x;
  const int lane = tid & 63;
  const int kh = tid >> 6;
  const int m0 = blockIdx.x * 16;
  const int n0 = blockIdx.y * 128;
  const int r = lane & 15;
  const int kg = lane >> 4;

  const __hip_bfloat16* pA = gs + (size_t)(m0 + r) * NG + kh * 1024 + kg * 8;
  const __hip_bfloat16* pB[8];
  #pragma unroll
  for (int i = 0; i < 8; ++i)
    pB[i] = Wd + (size_t)(n0 + i * 16 + r) * NG + kh * 1024 + kg * 8;

  f32x4 acc[8] = {};
  bf16x8 A0, A1, B0[8], B1[8];
  A0 = *(const bf16x8*)(pA);
  A1 = *(const bf16x8*)(pA + 32);
  #pragma unroll
  for (int i = 0; i < 8; ++i) {
    B0[i] = *(const bf16x8*)(pB[i]);
    B1[i] = *(const bf16x8*)(pB[i] + 32);
  }
  for (int c = 0; c < 32; c += 2) {
    {
      bf16x8 a = A0;
      bf16x8 bcur[8];
      #pragma unroll
      for (int i = 0; i < 8; ++i) bcur[i] = B0[i];
      if (c + 2 < 32) {
        A0 = *(const bf16x8*)(pA + (c + 2) * 32);
        #pragma unroll
        for (int i = 0; i < 8; ++i) B0[i] = *(const bf16x8*)(pB[i] + (c + 2) * 32);
      }
      #pragma unroll
      for (int i = 0; i < 8; ++i) acc[i] = mfma_bf16(a, bcur[i], acc[i]);
    }
    {
      bf16x8 a = A1;
      bf16x8 bcur[8];
      #pragma unroll
      for (int i = 0; i < 8; ++i) bcur[i] = B1[i];
      if (c + 3 < 32) {
        A1 = *(const bf16x8*)(pA + (c + 3) * 32);
        #pragma unroll
        for (int i = 0; i < 8; ++i) B1[i] = *(const bf16x8*)(pB[i] + (c + 3) * 32);
      }
      #pragma unroll
      for (int i = 0; i < 8; ++i) acc[i] = mfma_bf16(a, bcur[i], acc[i]);
    }
  }

  if (kh > 0) {
    #pragma unroll
    for (int j = 0; j < 4; ++j)
      #pragma unroll
      for (int i = 0; i < 8; ++i)
        sred[kh - 1][kg * 4 + j][i * 16 + r] = acc[i][j];
  }
  __syncthreads();
  if (kh == 0) {
    #pragma unroll
    for (int j = 0; j < 4; ++j) {
      const int row = kg * 4 + j;
      float* po = out + (size_t)(m0 + row) * NP + n0;
      #pragma unroll
      for (int i = 0; i < 8; ++i) {
        const int col = i * 16 + r;
        po[col] = acc[i][j] + sred[0][row][col] + sred[1][row][col]
                            + sred[2][row][col];
      }
    }
  }
}

// ---------------- log_softmax over rows of 512 (in place) ---------------
__global__ __launch_bounds__(256) void logsoftmax_kernel(float* __restrict__ out) {
  float* row = out + (size_t)blockIdx.x * NP;
  const int tid = threadIdx.x;
  const int lane = tid & 63, wid = tid >> 6;
  float x0 = row[tid], x1 = row[tid + 256];
  float m = fmaxf(x0, x1);
  #pragma unroll
  for (int off = 32; off >= 1; off >>= 1) m = fmaxf(m, __shfl_xor(m, off));
  __shared__ float sred[8];
  if (lane == 0) sred[wid] = m;
  __syncthreads();
  m = fmaxf(fmaxf(sred[0], sred[1]), fmaxf(sred[2], sred[3]));
  float e = __expf(x0 - m) + __expf(x1 - m);
  #pragma unroll
  for (int off = 32; off >= 1; off >>= 1) e += __shfl_xor(e, off);
  if (lane == 0) sred[4 + wid] = e;
  __syncthreads();
  float lse = m + __logf(sred[4] + sred[5] + sred[6] + sred[7]);
  row[tid] = x0 - lse;
  row[tid + 256] = x1 - lse;
}

extern "C" void kernel_launch(void* const* d_in, const int* in_sizes, int n_in,
                              void* d_out, int out_size, void* d_ws, size_t ws_size,
                              hipStream_t stream) {
  const float* v    = (const float*)d_in[0];  // [64,100,2]
  const float* p0   = (const float*)d_in[1];  // [64,512]
  const float* Wenc = (const float*)d_in[2];  // [4096,512]
  const float* Win  = (const float*)d_in[3];  // [4096,2]
  const float* Wh   = (const float*)d_in[4];  // [4096,4096]
  const float* Wdec = (const float*)d_in[5];  // [512,4096]
  float* out = (float*)d_out;                 // [64,100,512]

  char* ws = (char*)d_ws;
  __hip_bfloat16* gs      = (__hip_bfloat16*)(ws);               // 52,428,800
  __hip_bfloat16* Wh_bf   = (__hip_bfloat16*)(ws + 52428800);    // 33,554,432
  float*          zpart   = (float*)(ws + 85983232);             //  8,388,608
  __hip_bfloat16* Wdec_bf = (__hip_bfloat16*)(ws + 85983232);    // aliases zpart (used after RNN)
  float*          vv      = (float*)(ws + 94371840);             //  1,048,576
  float*          zp      = (float*)(ws + 95420416);             //  1,048,576
  __hip_bfloat16* h0_bf   = (__hip_bfloat16*)(ws + 96468992);    //    524,288
  // total 96,993,280 B

  hipMemsetAsync(vv, 0, 2 * 1048576, stream);   // vv + zp (contiguous)
  cvt_bf16_kernel<<<8192, 256, 0, stream>>>(Wh, Wh_bf, 2097152);
  encoder_kernel<<<256, 256, 0, stream>>>(p0, Wenc, h0_bf);

  for (int t = 0; t < T_STEPS; ++t) {
    const __hip_bfloat16* A = (t == 0) ? h0_bf : (gs + (size_t)(t - 1) * NG);
    int sA = (t == 0) ? NG : T_STEPS * NG;
    rnn_gemm_kernel<<<dim3(8, 64), 256, 0, stream>>>(A, sA, Wh_bf, zpart);
    rnn_epi_kernel<<<256, 256, 0, stream>>>(zpart, v, Win, vv, zp, gs, t);
  }

  cvt_bf16_kernel<<<1024, 256, 0, stream>>>(Wdec, Wdec_bf, 262144);  // after RNN (aliases zpart)
  decoder_kernel<<<dim3(400, 4), 256, 0, stream>>>(gs, Wdec_bf, out);
  logsoftmax_kernel<<<6400, 256, 0, stream>>>(out);
}

// Round 12
// 1253.937 us; speedup vs baseline: 2.0273x; 1.1326x over previous
//
#include <hip/hip_runtime.h>
#include <hip/hip_bf16.h>

#define T_STEPS 100
#define NG 4096
#define NP 512

typedef __bf16 bf16x8 __attribute__((ext_vector_type(8)));
typedef float f32x4 __attribute__((ext_vector_type(4)));

__device__ __forceinline__ f32x4 mfma_bf16(bf16x8 a, bf16x8 b, f32x4 c) {
  return __builtin_amdgcn_mfma_f32_16x16x32_bf16(a, b, c, 0, 0, 0);
}

// async global->LDS, 16B per lane; LDS dest = wave-uniform base + lane*16
__device__ __forceinline__ void gload16(const void* g, void* l) {
  __builtin_amdgcn_global_load_lds(
      (const __attribute__((address_space(1))) void*)g,
      (__attribute__((address_space(3))) void*)l, 16, 0, 0);
}

// ---------------- f32 -> bf16 conversion, 8 elems/thread ----------------
__global__ __launch_bounds__(256) void cvt_bf16_kernel(const float* __restrict__ in,
                                                       __hip_bfloat16* __restrict__ out,
                                                       int n8) {
  int i = blockIdx.x * 256 + threadIdx.x;
  if (i >= n8) return;
  const float4* p = reinterpret_cast<const float4*>(in) + (size_t)i * 2;
  float4 f0 = p[0], f1 = p[1];
  union { __hip_bfloat16 h[8]; uint4 u; } z;
  z.h[0] = __float2bfloat16(f0.x); z.h[1] = __float2bfloat16(f0.y);
  z.h[2] = __float2bfloat16(f0.z); z.h[3] = __float2bfloat16(f0.w);
  z.h[4] = __float2bfloat16(f1.x); z.h[5] = __float2bfloat16(f1.y);
  z.h[6] = __float2bfloat16(f1.z); z.h[7] = __float2bfloat16(f1.w);
  *(reinterpret_cast<uint4*>(out) + i) = z.u;
}

// ---------------- encoder: h0 = p0 @ W_enc^T  -> bf16 -------------------
__global__ __launch_bounds__(256) void encoder_kernel(const float* __restrict__ p0,
                                                      const float* __restrict__ Wenc,
                                                      __hip_bfloat16* __restrict__ h0) {
  __shared__ float sp[64 * 129];
  const int tid = threadIdx.x;
  const int nb = blockIdx.x * 16;
  const int b = tid & 63;
  const int jg = tid >> 6;
  float acc[4] = {0.f, 0.f, 0.f, 0.f};
  for (int kc = 0; kc < NP; kc += 128) {
    __syncthreads();
    #pragma unroll
    for (int i = 0; i < 32; ++i) {
      int e = tid + i * 256;
      int bb = e >> 7, kk = e & 127;
      sp[bb * 129 + kk] = p0[bb * NP + kc + kk];
    }
    __syncthreads();
    for (int kk = 0; kk < 128; ++kk) {
      float pv = sp[b * 129 + kk];
      #pragma unroll
      for (int jj = 0; jj < 4; ++jj)
        acc[jj] += pv * Wenc[(size_t)(nb + jg * 4 + jj) * NP + kc + kk];
    }
  }
  #pragma unroll
  for (int jj = 0; jj < 4; ++jj)
    h0[(size_t)b * NG + nb + jg * 4 + jj] = __float2bfloat16(acc[jj]);
}

// ---------------- RNN GEMM partial, LDS-staged (round-11 verbatim) ------
__global__ __launch_bounds__(256, 2) void rnn_gemm_kernel(
    const __hip_bfloat16* __restrict__ A, int strideA,
    const __hip_bfloat16* __restrict__ Wh,
    float* __restrict__ zpart) {
  __shared__ char smem[65536];   // [2 dbuf][A 16KB | B 16KB]
  const int tid = threadIdx.x;
  const int lane = tid & 63;
  const int w = tid >> 6;
  const int ms = w >> 1, ns = w & 1;
  const int kq = blockIdx.x, ng = blockIdx.y;
  const int r = lane & 15;
  const int kg = lane >> 4;
  const int n0 = ng * 64;

  const __hip_bfloat16* gA = A + (size_t)kq * 512;
  const __hip_bfloat16* gB = Wh + (size_t)n0 * NG + (size_t)kq * 512;

  const int xsw = (kg ^ (r & 3)) << 4;
  const int xA0 = (ms * 32 + r) * 256 + xsw;
  const int xA1 = xA0 + 16 * 256;
  const int xB0 = (ns * 32 + r) * 256 + xsw;
  const int xB1 = xB0 + 16 * 256;
  const int x6 = (r & 4) << 4;
  const int ksX[4] = {0 ^ x6, 64 ^ x6, 128 ^ x6, 192 ^ x6};

  auto stageA = [&](int buf, int it) {
    #pragma unroll
    for (int i = 0; i < 4; ++i) {
      int c = i * 256 + tid;
      int row = c >> 4;
      int colB = (c & 15) * 16;
      int srcB = colB ^ ((row & 7) << 4);
      const char* src = (const char*)(gA + (size_t)row * strideA + it * 128) + srcB;
      gload16(src, smem + buf * 32768 + i * 4096 + w * 1024);
    }
  };
  auto stageB = [&](int buf, int it) {
    #pragma unroll
    for (int i = 0; i < 4; ++i) {
      int c = i * 256 + tid;
      int row = c >> 4;
      int colB = (c & 15) * 16;
      int srcB = colB ^ ((row & 7) << 4);
      const char* src = (const char*)(gB + (size_t)row * NG + it * 128) + srcB;
      gload16(src, smem + buf * 32768 + 16384 + i * 4096 + w * 1024);
    }
  };

  stageA(0, 0);
  stageB(0, 0);
  asm volatile("s_waitcnt vmcnt(0)" ::: "memory");
  __syncthreads();

  f32x4 acc00{}, acc01{}, acc10{}, acc11{};
  #pragma unroll
  for (int it = 0; it < 4; ++it) {
    const int buf = it & 1;
    if (it < 3) { stageA(buf ^ 1, it + 1); stageB(buf ^ 1, it + 1); }
    const char* bA = smem + buf * 32768;
    const char* bB = bA + 16384;
    #pragma unroll
    for (int ks = 0; ks < 4; ++ks) {
      bf16x8 a0 = *(const bf16x8*)(bA + xA0 + ksX[ks]);
      bf16x8 a1 = *(const bf16x8*)(bA + xA1 + ksX[ks]);
      bf16x8 b0 = *(const bf16x8*)(bB + xB0 + ksX[ks]);
      bf16x8 b1 = *(const bf16x8*)(bB + xB1 + ksX[ks]);
      acc00 = mfma_bf16(a0, b0, acc00);
      acc01 = mfma_bf16(a0, b1, acc01);
      acc10 = mfma_bf16(a1, b0, acc10);
      acc11 = mfma_bf16(a1, b1, acc11);
    }
    asm volatile("s_waitcnt vmcnt(0)" ::: "memory");
    __syncthreads();
  }

  float* zb = zpart + ((size_t)(kq * 64 + ms * 32 + kg * 4) << 12) + n0 + ns * 32 + r;
  #pragma unroll
  for (int j = 0; j < 4; ++j) {
    zb[(size_t)j * NG]             = acc00[j];
    zb[(size_t)j * NG + 16]        = acc01[j];
    zb[(size_t)(16 + j) * NG]      = acc10[j];
    zb[(size_t)(16 + j) * NG + 16] = acc11[j];
  }
}

// ---------------- RNN epilogue: sum partials + recurrence + relu --------
__global__ __launch_bounds__(256) void rnn_epi_kernel(
    const float* __restrict__ zpart,
    const float* __restrict__ v, const float* __restrict__ Win,
    float* __restrict__ vv, float* __restrict__ zp,
    __hip_bfloat16* __restrict__ gs, int t) {
  const int g = blockIdx.x * 256 + threadIdx.x;   // 0..65535
  const int b = g >> 10;
  const int n = (g & 1023) * 4;
  f32x4 s{};
  #pragma unroll
  for (int kq = 0; kq < 8; ++kq)
    s += *(const f32x4*)(zpart + ((size_t)(kq * 64 + b) << 12) + n);
  float2 vt = *(const float2*)(v + (b * T_STEPS + t) * 2);
  float4 wA = *(const float4*)(Win + 2 * n);
  float4 wB = *(const float4*)(Win + 2 * n + 4);
  f32x4 z;
  z[0] = s[0] + vt.x * wA.x + vt.y * wA.y;
  z[1] = s[1] + vt.x * wA.z + vt.y * wA.w;
  z[2] = s[2] + vt.x * wB.x + vt.y * wB.y;
  z[3] = s[3] + vt.x * wB.z + vt.y * wB.w;
  f32x4 vvo = *(const f32x4*)(vv + (size_t)b * NG + n);
  f32x4 zpo = *(const f32x4*)(zp + (size_t)b * NG + n);
  union { __hip_bfloat16 h[4]; uint2 u2; } o;
  f32x4 vvn;
  #pragma unroll
  for (int j = 0; j < 4; ++j) {
    z[j] -= 0.5f * vvo[j];                       // z uses OLD vv
    vvn[j] = fmaxf(vvo[j] + 0.1f * (zpo[j] - vvo[j]), 0.f);
    o.h[j] = __float2bfloat16(fmaxf(z[j], 0.f));
  }
  *(f32x4*)(vv + (size_t)b * NG + n) = vvn;
  *(f32x4*)(zp + (size_t)b * NG + n) = z;        // pre-relu z
  *(uint2*)(gs + (size_t)(b * T_STEPS + t) * NG + n) = o.u2;
}

// ---------------- decoder: logits = gs @ W_dec^T, LDS-staged ------------
// 800 blocks linear; mapping: xcd = bid&7, i = bid>>3, mtile = xcd*25 + i%25,
// ntile = i/25. Each XCD owns a contiguous 800-row gs band (6.4 MB) and Wd
// (4 MB) -> ~L2-resident; every gs row read by exactly ONE XCD.
// Block tile 32m x 128n, BK=64, 40 KB LDS dbuf (4 blocks/CU). 4 waves, wave
// ns: 32m x 32n, 2x2 frags = 4 chains. global_load_lds + both-sides XOR
// swizzle (row stride 128B => 16-way conflict unswizzled).
__global__ __launch_bounds__(256, 4) void decoder_kernel(
    const __hip_bfloat16* __restrict__ gs,
    const __hip_bfloat16* __restrict__ Wd,
    float* __restrict__ out) {
  __shared__ char smem[40960];    // [2 dbuf][A 4KB | B 16KB]
  const int tid = threadIdx.x;
  const int lane = tid & 63;
  const int w = tid >> 6;         // wave = ns (n sub-tile)
  const int bid = blockIdx.x;
  const int xcd = bid & 7;
  const int i6 = bid >> 3;        // 0..99
  const int mtile = xcd * 25 + (i6 % 25);
  const int ntile = i6 / 25;
  const int m0 = mtile * 32;
  const int n0 = ntile * 128;
  const int r = lane & 15;
  const int kg = lane >> 4;

  const __hip_bfloat16* gA = gs + (size_t)m0 * NG;
  const __hip_bfloat16* gB = Wd + (size_t)n0 * NG;

  // read offsets: row stride 128B; XOR (row&7)<<4 split per-lane/slot
  const int xsw = (kg * 16) ^ ((r & 3) << 4);
  const int x6 = (r & 4) << 4;
  const int ksX[2] = {0 ^ x6, 64 ^ x6};
  const int xA0 = r * 128 + xsw;
  const int xA1 = xA0 + 16 * 128;
  const int xB0 = (w * 32 + r) * 128 + xsw;
  const int xB1 = xB0 + 16 * 128;

  // A tile 32x64 bf16 = 4KB = 256 chunks (1 call); B tile 128x64 = 16KB (4)
  auto stageA = [&](int buf, int it) {
    int row = tid >> 3;
    int colB = (tid & 7) * 16;
    int srcB = colB ^ ((row & 7) << 4);
    const char* src = (const char*)(gA + (size_t)row * NG + it * 64) + srcB;
    gload16(src, smem + buf * 20480 + w * 1024);
  };
  auto stageB = [&](int buf, int it) {
    #pragma unroll
    for (int i = 0; i < 4; ++i) {
      int c = i * 256 + tid;
      int row = c >> 3;
      int colB = (c & 7) * 16;
      int srcB = colB ^ ((row & 7) << 4);
      const char* src = (const char*)(gB + (size_t)row * NG + it * 64) + srcB;
      gload16(src, smem + buf * 20480 + 4096 + i * 4096 + w * 1024);
    }
  };

  stageA(0, 0);
  stageB(0, 0);
  asm volatile("s_waitcnt vmcnt(0)" ::: "memory");
  __syncthreads();

  f32x4 acc00{}, acc01{}, acc10{}, acc11{};
  #pragma unroll 2
  for (int it = 0; it < 64; ++it) {
    const int buf = it & 1;
    if (it < 63) { stageA(buf ^ 1, it + 1); stageB(buf ^ 1, it + 1); }
    const char* bA = smem + buf * 20480;
    const char* bB = bA + 4096;
    #pragma unroll
    for (int ks = 0; ks < 2; ++ks) {
      bf16x8 a0 = *(const bf16x8*)(bA + xA0 + ksX[ks]);
      bf16x8 a1 = *(const bf16x8*)(bA + xA1 + ksX[ks]);
      bf16x8 b0 = *(const bf16x8*)(bB + xB0 + ksX[ks]);
      bf16x8 b1 = *(const bf16x8*)(bB + xB1 + ksX[ks]);
      acc00 = mfma_bf16(a0, b0, acc00);
      acc01 = mfma_bf16(a0, b1, acc01);
      acc10 = mfma_bf16(a1, b0, acc10);
      acc11 = mfma_bf16(a1, b1, acc11);
    }
    asm volatile("s_waitcnt vmcnt(0)" ::: "memory");
    __syncthreads();
  }

  // C: row = m0 + fi*16 + kg*4 + j; col = n0 + w*32 + fj*16 + r
  #pragma unroll
  for (int j = 0; j < 4; ++j) {
    float* po0 = out + (size_t)(m0 + kg * 4 + j) * NP + n0 + w * 32;
    float* po1 = out + (size_t)(m0 + 16 + kg * 4 + j) * NP + n0 + w * 32;
    po0[r]      = acc00[j];
    po0[r + 16] = acc01[j];
    po1[r]      = acc10[j];
    po1[r + 16] = acc11[j];
  }
}

// ---------------- log_softmax over rows of 512 (in place) ---------------
__global__ __launch_bounds__(256) void logsoftmax_kernel(float* __restrict__ out) {
  float* row = out + (size_t)blockIdx.x * NP;
  const int tid = threadIdx.x;
  const int lane = tid & 63, wid = tid >> 6;
  float x0 = row[tid], x1 = row[tid + 256];
  float m = fmaxf(x0, x1);
  #pragma unroll
  for (int off = 32; off >= 1; off >>= 1) m = fmaxf(m, __shfl_xor(m, off));
  __shared__ float sred[8];
  if (lane == 0) sred[wid] = m;
  __syncthreads();
  m = fmaxf(fmaxf(sred[0], sred[1]), fmaxf(sred[2], sred[3]));
  float e = __expf(x0 - m) + __expf(x1 - m);
  #pragma unroll
  for (int off = 32; off >= 1; off >>= 1) e += __shfl_xor(e, off);
  if (lane == 0) sred[4 + wid] = e;
  __syncthreads();
  float lse = m + __logf(sred[4] + sred[5] + sred[6] + sred[7]);
  row[tid] = x0 - lse;
  row[tid + 256] = x1 - lse;
}

extern "C" void kernel_launch(void* const* d_in, const int* in_sizes, int n_in,
                              void* d_out, int out_size, void* d_ws, size_t ws_size,
                              hipStream_t stream) {
  const float* v    = (const float*)d_in[0];  // [64,100,2]
  const float* p0   = (const float*)d_in[1];  // [64,512]
  const float* Wenc = (const float*)d_in[2];  // [4096,512]
  const float* Win  = (const float*)d_in[3];  // [4096,2]
  const float* Wh   = (const float*)d_in[4];  // [4096,4096]
  const float* Wdec = (const float*)d_in[5];  // [512,4096]
  float* out = (float*)d_out;                 // [64,100,512]

  char* ws = (char*)d_ws;
  __hip_bfloat16* gs      = (__hip_bfloat16*)(ws);               // 52,428,800
  __hip_bfloat16* Wh_bf   = (__hip_bfloat16*)(ws + 52428800);    // 33,554,432
  float*          zpart   = (float*)(ws + 85983232);             //  8,388,608
  __hip_bfloat16* Wdec_bf = (__hip_bfloat16*)(ws + 85983232);    // aliases zpart (used after RNN)
  float*          vv      = (float*)(ws + 94371840);             //  1,048,576
  float*          zp      = (float*)(ws + 95420416);             //  1,048,576
  __hip_bfloat16* h0_bf   = (__hip_bfloat16*)(ws + 96468992);    //    524,288
  // total 96,993,280 B

  hipMemsetAsync(vv, 0, 2 * 1048576, stream);   // vv + zp (contiguous)
  cvt_bf16_kernel<<<8192, 256, 0, stream>>>(Wh, Wh_bf, 2097152);
  encoder_kernel<<<256, 256, 0, stream>>>(p0, Wenc, h0_bf);

  for (int t = 0; t < T_STEPS; ++t) {
    const __hip_bfloat16* A = (t == 0) ? h0_bf : (gs + (size_t)(t - 1) * NG);
    int sA = (t == 0) ? NG : T_STEPS * NG;
    rnn_gemm_kernel<<<dim3(8, 64), 256, 0, stream>>>(A, sA, Wh_bf, zpart);
    rnn_epi_kernel<<<256, 256, 0, stream>>>(zpart, v, Win, vv, zp, gs, t);
  }

  cvt_bf16_kernel<<<1024, 256, 0, stream>>>(Wdec, Wdec_bf, 262144);  // after RNN (aliases zpart)
  decoder_kernel<<<800, 256, 0, stream>>>(gs, Wdec_bf, out);
  logsoftmax_kernel<<<6400, 256, 0, stream>>>(out);
}

// Round 13
// 1235.373 us; speedup vs baseline: 2.0577x; 1.0150x over previous
//
#include <hip/hip_runtime.h>
#include <hip/hip_bf16.h>

#define T_STEPS 100
#define NG 4096
#define NP 512

typedef __bf16 bf16x8 __attribute__((ext_vector_type(8)));
typedef float f32x4 __attribute__((ext_vector_type(4)));

__device__ __forceinline__ f32x4 mfma_bf16(bf16x8 a, bf16x8 b, f32x4 c) {
  return __builtin_amdgcn_mfma_f32_16x16x32_bf16(a, b, c, 0, 0, 0);
}

// async global->LDS, 16B per lane; LDS dest = wave-uniform base + lane*16
__device__ __forceinline__ void gload16(const void* g, void* l) {
  __builtin_amdgcn_global_load_lds(
      (const __attribute__((address_space(1))) void*)g,
      (__attribute__((address_space(3))) void*)l, 16, 0, 0);
}

// ---------------- f32 -> bf16 conversion, 8 elems/thread ----------------
__global__ __launch_bounds__(256) void cvt_bf16_kernel(const float* __restrict__ in,
                                                       __hip_bfloat16* __restrict__ out,
                                                       int n8) {
  int i = blockIdx.x * 256 + threadIdx.x;
  if (i >= n8) return;
  const float4* p = reinterpret_cast<const float4*>(in) + (size_t)i * 2;
  float4 f0 = p[0], f1 = p[1];
  union { __hip_bfloat16 h[8]; uint4 u; } z;
  z.h[0] = __float2bfloat16(f0.x); z.h[1] = __float2bfloat16(f0.y);
  z.h[2] = __float2bfloat16(f0.z); z.h[3] = __float2bfloat16(f0.w);
  z.h[4] = __float2bfloat16(f1.x); z.h[5] = __float2bfloat16(f1.y);
  z.h[6] = __float2bfloat16(f1.z); z.h[7] = __float2bfloat16(f1.w);
  *(reinterpret_cast<uint4*>(out) + i) = z.u;
}

// ---------------- encoder: h0 = p0 @ W_enc^T  -> bf16 -------------------
__global__ __launch_bounds__(256) void encoder_kernel(const float* __restrict__ p0,
                                                      const float* __restrict__ Wenc,
                                                      __hip_bfloat16* __restrict__ h0) {
  __shared__ float sp[64 * 129];
  const int tid = threadIdx.x;
  const int nb = blockIdx.x * 16;
  const int b = tid & 63;
  const int jg = tid >> 6;
  float acc[4] = {0.f, 0.f, 0.f, 0.f};
  for (int kc = 0; kc < NP; kc += 128) {
    __syncthreads();
    #pragma unroll
    for (int i = 0; i < 32; ++i) {
      int e = tid + i * 256;
      int bb = e >> 7, kk = e & 127;
      sp[bb * 129 + kk] = p0[bb * NP + kc + kk];
    }
    __syncthreads();
    for (int kk = 0; kk < 128; ++kk) {
      float pv = sp[b * 129 + kk];
      #pragma unroll
      for (int jj = 0; jj < 4; ++jj)
        acc[jj] += pv * Wenc[(size_t)(nb + jg * 4 + jj) * NP + kc + kk];
    }
  }
  #pragma unroll
  for (int jj = 0; jj < 4; ++jj)
    h0[(size_t)b * NG + nb + jg * 4 + jj] = __float2bfloat16(acc[jj]);
}

// ---------------- RNN GEMM partial, 3-buffer ring + counted vmcnt -------
// grid (8 kq, 64 ng) -- kq fastest => XCD = kq (A slice + zpart L2-local).
// Block 256 = 4 waves (ms,ns 2x2), tile 64b x 64n x 512k, BK=64 -> 8 iters.
// LDS: 3 bufs x (A 8KB | B 8KB) = 48 KB -> 3 blocks/CU.
// Ring: stages issued 2 ahead; per-iter s_waitcnt vmcnt(4) waits ONLY the
// buffer about to be consumed (newest stage's 4 ops stay in flight) + raw
// s_barrier + sched_barrier(0) (rule-18 fence). Window it: reads buf it%3,
// gload-writes buf (it+2)%3 -- disjoint; reads complete before the barrier
// that opens the overwrite (ds_read -> MFMA -> barrier program order).
// k ascending (it*64 + ks*32) == r4 order => zpart bitwise identical.
// Staging swizzle: byte ^= (row&7)<<4 on src, same XOR on ds_read (proven).
__global__ __launch_bounds__(256, 3) void rnn_gemm_kernel(
    const __hip_bfloat16* __restrict__ A, int strideA,
    const __hip_bfloat16* __restrict__ Wh,
    float* __restrict__ zpart) {
  __shared__ char smem[49152];   // [3 bufs][A 8KB | B 8KB]
  const int tid = threadIdx.x;
  const int lane = tid & 63;
  const int w = tid >> 6;
  const int ms = w >> 1, ns = w & 1;
  const int kq = blockIdx.x, ng = blockIdx.y;
  const int r = lane & 15;
  const int kg = lane >> 4;
  const int n0 = ng * 64;

  const __hip_bfloat16* gA = A + (size_t)kq * 512;
  const __hip_bfloat16* gB = Wh + (size_t)n0 * NG + (size_t)kq * 512;

  // read offsets: row stride 128B (BK=64); XOR bits 4-5 per-lane, bit 6 slot
  const int xsw = (kg ^ (r & 3)) << 4;
  const int x6 = (r & 4) << 4;
  const int ksX[2] = {0 ^ x6, 64 ^ x6};
  const int xA0 = (ms * 32 + r) * 128 + xsw;
  const int xA1 = xA0 + 16 * 128;
  const int xB0 = 8192 + (ns * 32 + r) * 128 + xsw;
  const int xB1 = xB0 + 16 * 128;

  // one 64x64 bf16 tile = 8KB = 512 chunks; 2 calls/thread (4 per A+B stage)
  auto stageA = [&](int buf, int it) {
    #pragma unroll
    for (int i = 0; i < 2; ++i) {
      int c = i * 256 + tid;
      int row = c >> 3;               // 8 chunks per 128B row
      int colB = (c & 7) * 16;
      int srcB = colB ^ ((row & 7) << 4);
      const char* src = (const char*)(gA + (size_t)row * strideA + it * 64) + srcB;
      gload16(src, smem + buf * 16384 + i * 4096 + w * 1024);
    }
  };
  auto stageB = [&](int buf, int it) {
    #pragma unroll
    for (int i = 0; i < 2; ++i) {
      int c = i * 256 + tid;
      int row = c >> 3;
      int colB = (c & 7) * 16;
      int srcB = colB ^ ((row & 7) << 4);
      const char* src = (const char*)(gB + (size_t)row * NG + it * 64) + srcB;
      gload16(src, smem + buf * 16384 + 8192 + i * 4096 + w * 1024);
    }
  };

  stageA(0, 0); stageB(0, 0);       // 4 ops
  stageA(1, 1); stageB(1, 1);       // 8 ops outstanding

  f32x4 acc00{}, acc01{}, acc10{}, acc11{};
  #pragma unroll
  for (int it = 0; it < 8; ++it) {
    if (it == 7) asm volatile("s_waitcnt vmcnt(0)" ::: "memory");
    else         asm volatile("s_waitcnt vmcnt(4)" ::: "memory");
    __builtin_amdgcn_s_barrier();
    __builtin_amdgcn_sched_barrier(0);
    if (it < 6) { stageA((it + 2) % 3, it + 2); stageB((it + 2) % 3, it + 2); }
    const char* bb = smem + (it % 3) * 16384;
    #pragma unroll
    for (int ks = 0; ks < 2; ++ks) {          // k = it*64 + ks*32 ascending
      bf16x8 a0 = *(const bf16x8*)(bb + xA0 + ksX[ks]);
      bf16x8 a1 = *(const bf16x8*)(bb + xA1 + ksX[ks]);
      bf16x8 b0 = *(const bf16x8*)(bb + xB0 + ksX[ks]);
      bf16x8 b1 = *(const bf16x8*)(bb + xB1 + ksX[ks]);
      acc00 = mfma_bf16(a0, b0, acc00);
      acc01 = mfma_bf16(a0, b1, acc01);
      acc10 = mfma_bf16(a1, b0, acc10);
      acc11 = mfma_bf16(a1, b1, acc11);
    }
  }

  // store: C row b = ms*32 + fi*16 + kg*4 + j; col n = n0 + ns*32 + fj*16 + r
  float* zb = zpart + ((size_t)(kq * 64 + ms * 32 + kg * 4) << 12) + n0 + ns * 32 + r;
  #pragma unroll
  for (int j = 0; j < 4; ++j) {
    zb[(size_t)j * NG]             = acc00[j];
    zb[(size_t)j * NG + 16]        = acc01[j];
    zb[(size_t)(16 + j) * NG]      = acc10[j];
    zb[(size_t)(16 + j) * NG + 16] = acc11[j];
  }
}

// ---------------- RNN epilogue: sum partials + recurrence + relu --------
__global__ __launch_bounds__(256) void rnn_epi_kernel(
    const float* __restrict__ zpart,
    const float* __restrict__ v, const float* __restrict__ Win,
    float* __restrict__ vv, float* __restrict__ zp,
    __hip_bfloat16* __restrict__ gs, int t) {
  const int g = blockIdx.x * 256 + threadIdx.x;   // 0..65535
  const int b = g >> 10;
  const int n = (g & 1023) * 4;
  f32x4 s{};
  #pragma unroll
  for (int kq = 0; kq < 8; ++kq)
    s += *(const f32x4*)(zpart + ((size_t)(kq * 64 + b) << 12) + n);
  float2 vt = *(const float2*)(v + (b * T_STEPS + t) * 2);
  float4 wA = *(const float4*)(Win + 2 * n);
  float4 wB = *(const float4*)(Win + 2 * n + 4);
  f32x4 z;
  z[0] = s[0] + vt.x * wA.x + vt.y * wA.y;
  z[1] = s[1] + vt.x * wA.z + vt.y * wA.w;
  z[2] = s[2] + vt.x * wB.x + vt.y * wB.y;
  z[3] = s[3] + vt.x * wB.z + vt.y * wB.w;
  f32x4 vvo = *(const f32x4*)(vv + (size_t)b * NG + n);
  f32x4 zpo = *(const f32x4*)(zp + (size_t)b * NG + n);
  union { __hip_bfloat16 h[4]; uint2 u2; } o;
  f32x4 vvn;
  #pragma unroll
  for (int j = 0; j < 4; ++j) {
    z[j] -= 0.5f * vvo[j];                       // z uses OLD vv
    vvn[j] = fmaxf(vvo[j] + 0.1f * (zpo[j] - vvo[j]), 0.f);
    o.h[j] = __float2bfloat16(fmaxf(z[j], 0.f));
  }
  *(f32x4*)(vv + (size_t)b * NG + n) = vvn;
  *(f32x4*)(zp + (size_t)b * NG + n) = z;        // pre-relu z
  *(uint2*)(gs + (size_t)(b * T_STEPS + t) * NG + n) = o.u2;
}

// ---------------- decoder: logits = gs @ W_dec^T, LDS-staged (r12) ------
__global__ __launch_bounds__(256, 4) void decoder_kernel(
    const __hip_bfloat16* __restrict__ gs,
    const __hip_bfloat16* __restrict__ Wd,
    float* __restrict__ out) {
  __shared__ char smem[40960];    // [2 dbuf][A 4KB | B 16KB]
  const int tid = threadIdx.x;
  const int lane = tid & 63;
  const int w = tid >> 6;         // wave = ns (n sub-tile)
  const int bid = blockIdx.x;
  const int xcd = bid & 7;
  const int i6 = bid >> 3;        // 0..99
  const int mtile = xcd * 25 + (i6 % 25);
  const int ntile = i6 / 25;
  const int m0 = mtile * 32;
  const int n0 = ntile * 128;
  const int r = lane & 15;
  const int kg = lane >> 4;

  const __hip_bfloat16* gA = gs + (size_t)m0 * NG;
  const __hip_bfloat16* gB = Wd + (size_t)n0 * NG;

  const int xsw = (kg * 16) ^ ((r & 3) << 4);
  const int x6 = (r & 4) << 4;
  const int ksX[2] = {0 ^ x6, 64 ^ x6};
  const int xA0 = r * 128 + xsw;
  const int xA1 = xA0 + 16 * 128;
  const int xB0 = (w * 32 + r) * 128 + xsw;
  const int xB1 = xB0 + 16 * 128;

  auto stageA = [&](int buf, int it) {
    int row = tid >> 3;
    int colB = (tid & 7) * 16;
    int srcB = colB ^ ((row & 7) << 4);
    const char* src = (const char*)(gA + (size_t)row * NG + it * 64) + srcB;
    gload16(src, smem + buf * 20480 + w * 1024);
  };
  auto stageB = [&](int buf, int it) {
    #pragma unroll
    for (int i = 0; i < 4; ++i) {
      int c = i * 256 + tid;
      int row = c >> 3;
      int colB = (c & 7) * 16;
      int srcB = colB ^ ((row & 7) << 4);
      const char* src = (const char*)(gB + (size_t)row * NG + it * 64) + srcB;
      gload16(src, smem + buf * 20480 + 4096 + i * 4096 + w * 1024);
    }
  };

  stageA(0, 0);
  stageB(0, 0);
  asm volatile("s_waitcnt vmcnt(0)" ::: "memory");
  __syncthreads();

  f32x4 acc00{}, acc01{}, acc10{}, acc11{};
  #pragma unroll 2
  for (int it = 0; it < 64; ++it) {
    const int buf = it & 1;
    if (it < 63) { stageA(buf ^ 1, it + 1); stageB(buf ^ 1, it + 1); }
    const char* bA = smem + buf * 20480;
    const char* bB = bA + 4096;
    #pragma unroll
    for (int ks = 0; ks < 2; ++ks) {
      bf16x8 a0 = *(const bf16x8*)(bA + xA0 + ksX[ks]);
      bf16x8 a1 = *(const bf16x8*)(bA + xA1 + ksX[ks]);
      bf16x8 b0 = *(const bf16x8*)(bB + xB0 + ksX[ks]);
      bf16x8 b1 = *(const bf16x8*)(bB + xB1 + ksX[ks]);
      acc00 = mfma_bf16(a0, b0, acc00);
      acc01 = mfma_bf16(a0, b1, acc01);
      acc10 = mfma_bf16(a1, b0, acc10);
      acc11 = mfma_bf16(a1, b1, acc11);
    }
    asm volatile("s_waitcnt vmcnt(0)" ::: "memory");
    __syncthreads();
  }

  #pragma unroll
  for (int j = 0; j < 4; ++j) {
    float* po0 = out + (size_t)(m0 + kg * 4 + j) * NP + n0 + w * 32;
    float* po1 = out + (size_t)(m0 + 16 + kg * 4 + j) * NP + n0 + w * 32;
    po0[r]      = acc00[j];
    po0[r + 16] = acc01[j];
    po1[r]      = acc10[j];
    po1[r + 16] = acc11[j];
  }
}

// ---------------- log_softmax over rows of 512 (in place) ---------------
__global__ __launch_bounds__(256) void logsoftmax_kernel(float* __restrict__ out) {
  float* row = out + (size_t)blockIdx.x * NP;
  const int tid = threadIdx.x;
  const int lane = tid & 63, wid = tid >> 6;
  float x0 = row[tid], x1 = row[tid + 256];
  float m = fmaxf(x0, x1);
  #pragma unroll
  for (int off = 32; off >= 1; off >>= 1) m = fmaxf(m, __shfl_xor(m, off));
  __shared__ float sred[8];
  if (lane == 0) sred[wid] = m;
  __syncthreads();
  m = fmaxf(fmaxf(sred[0], sred[1]), fmaxf(sred[2], sred[3]));
  float e = __expf(x0 - m) + __expf(x1 - m);
  #pragma unroll
  for (int off = 32; off >= 1; off >>= 1) e += __shfl_xor(e, off);
  if (lane == 0) sred[4 + wid] = e;
  __syncthreads();
  float lse = m + __logf(sred[4] + sred[5] + sred[6] + sred[7]);
  row[tid] = x0 - lse;
  row[tid + 256] = x1 - lse;
}

extern "C" void kernel_launch(void* const* d_in, const int* in_sizes, int n_in,
                              void* d_out, int out_size, void* d_ws, size_t ws_size,
                              hipStream_t stream) {
  const float* v    = (const float*)d_in[0];  // [64,100,2]
  const float* p0   = (const float*)d_in[1];  // [64,512]
  const float* Wenc = (const float*)d_in[2];  // [4096,512]
  const float* Win  = (const float*)d_in[3];  // [4096,2]
  const float* Wh   = (const float*)d_in[4];  // [4096,4096]
  const float* Wdec = (const float*)d_in[5];  // [512,4096]
  float* out = (float*)d_out;                 // [64,100,512]

  char* ws = (char*)d_ws;
  __hip_bfloat16* gs      = (__hip_bfloat16*)(ws);               // 52,428,800
  __hip_bfloat16* Wh_bf   = (__hip_bfloat16*)(ws + 52428800);    // 33,554,432
  float*          zpart   = (float*)(ws + 85983232);             //  8,388,608
  __hip_bfloat16* Wdec_bf = (__hip_bfloat16*)(ws + 85983232);    // aliases zpart (used after RNN)
  float*          vv      = (float*)(ws + 94371840);             //  1,048,576
  float*          zp      = (float*)(ws + 95420416);             //  1,048,576
  __hip_bfloat16* h0_bf   = (__hip_bfloat16*)(ws + 96468992);    //    524,288
  // total 96,993,280 B

  hipMemsetAsync(vv, 0, 2 * 1048576, stream);   // vv + zp (contiguous)
  cvt_bf16_kernel<<<8192, 256, 0, stream>>>(Wh, Wh_bf, 2097152);
  encoder_kernel<<<256, 256, 0, stream>>>(p0, Wenc, h0_bf);

  for (int t = 0; t < T_STEPS; ++t) {
    const __hip_bfloat16* A = (t == 0) ? h0_bf : (gs + (size_t)(t - 1) * NG);
    int sA = (t == 0) ? NG : T_STEPS * NG;
    rnn_gemm_kernel<<<dim3(8, 64), 256, 0, stream>>>(A, sA, Wh_bf, zpart);
    rnn_epi_kernel<<<256, 256, 0, stream>>>(zpart, v, Win, vv, zp, gs, t);
  }

  cvt_bf16_kernel<<<1024, 256, 0, stream>>>(Wdec, Wdec_bf, 262144);  // after RNN (aliases zpart)
  decoder_kernel<<<800, 256, 0, stream>>>(gs, Wdec_bf, out);
  logsoftmax_kernel<<<6400, 256, 0, stream>>>(out);
}

// Round 14
// 1128.748 us; speedup vs baseline: 2.2521x; 1.0945x over previous
//
#include <hip/hip_runtime.h>
#include <hip/hip_bf16.h>

#define T_STEPS 100
#define NG 4096
#define NP 512

typedef __bf16 bf16x8 __attribute__((ext_vector_type(8)));
typedef float f32x4 __attribute__((ext_vector_type(4)));

__device__ __forceinline__ f32x4 mfma_bf16(bf16x8 a, bf16x8 b, f32x4 c) {
  return __builtin_amdgcn_mfma_f32_16x16x32_bf16(a, b, c, 0, 0, 0);
}

// async global->LDS, 16B per lane; LDS dest = wave-uniform base + lane*16
__device__ __forceinline__ void gload16(const void* g, void* l) {
  __builtin_amdgcn_global_load_lds(
      (const __attribute__((address_space(1))) void*)g,
      (__attribute__((address_space(3))) void*)l, 16, 0, 0);
}

// ---------------- f32 -> bf16 conversion, 8 elems/thread ----------------
__global__ __launch_bounds__(256) void cvt_bf16_kernel(const float* __restrict__ in,
                                                       __hip_bfloat16* __restrict__ out,
                                                       int n8) {
  int i = blockIdx.x * 256 + threadIdx.x;
  if (i >= n8) return;
  const float4* p = reinterpret_cast<const float4*>(in) + (size_t)i * 2;
  float4 f0 = p[0], f1 = p[1];
  union { __hip_bfloat16 h[8]; uint4 u; } z;
  z.h[0] = __float2bfloat16(f0.x); z.h[1] = __float2bfloat16(f0.y);
  z.h[2] = __float2bfloat16(f0.z); z.h[3] = __float2bfloat16(f0.w);
  z.h[4] = __float2bfloat16(f1.x); z.h[5] = __float2bfloat16(f1.y);
  z.h[6] = __float2bfloat16(f1.z); z.h[7] = __float2bfloat16(f1.w);
  *(reinterpret_cast<uint4*>(out) + i) = z.u;
}

// ---------------- encoder: h0 = p0 @ W_enc^T  -> bf16 -------------------
__global__ __launch_bounds__(256) void encoder_kernel(const float* __restrict__ p0,
                                                      const float* __restrict__ Wenc,
                                                      __hip_bfloat16* __restrict__ h0) {
  __shared__ float sp[64 * 129];
  const int tid = threadIdx.x;
  const int nb = blockIdx.x * 16;
  const int b = tid & 63;
  const int jg = tid >> 6;
  float acc[4] = {0.f, 0.f, 0.f, 0.f};
  for (int kc = 0; kc < NP; kc += 128) {
    __syncthreads();
    #pragma unroll
    for (int i = 0; i < 32; ++i) {
      int e = tid + i * 256;
      int bb = e >> 7, kk = e & 127;
      sp[bb * 129 + kk] = p0[bb * NP + kc + kk];
    }
    __syncthreads();
    for (int kk = 0; kk < 128; ++kk) {
      float pv = sp[b * 129 + kk];
      #pragma unroll
      for (int jj = 0; jj < 4; ++jj)
        acc[jj] += pv * Wenc[(size_t)(nb + jg * 4 + jj) * NP + kc + kk];
    }
  }
  #pragma unroll
  for (int jj = 0; jj < 4; ++jj)
    h0[(size_t)b * NG + nb + jg * 4 + jj] = __float2bfloat16(acc[jj]);
}

// ---------------- RNN GEMM partial, 3-buffer ring + counted vmcnt -------
// (round-13 structure; zpart now bf16 -> halves store, dispatch-end L2
// writeback, and epi read traffic. k order unchanged.)
__global__ __launch_bounds__(256, 3) void rnn_gemm_kernel(
    const __hip_bfloat16* __restrict__ A, int strideA,
    const __hip_bfloat16* __restrict__ Wh,
    __hip_bfloat16* __restrict__ zpart) {
  __shared__ char smem[49152];   // [3 bufs][A 8KB | B 8KB]
  const int tid = threadIdx.x;
  const int lane = tid & 63;
  const int w = tid >> 6;
  const int ms = w >> 1, ns = w & 1;
  const int kq = blockIdx.x, ng = blockIdx.y;
  const int r = lane & 15;
  const int kg = lane >> 4;
  const int n0 = ng * 64;

  const __hip_bfloat16* gA = A + (size_t)kq * 512;
  const __hip_bfloat16* gB = Wh + (size_t)n0 * NG + (size_t)kq * 512;

  const int xsw = (kg ^ (r & 3)) << 4;
  const int x6 = (r & 4) << 4;
  const int ksX[2] = {0 ^ x6, 64 ^ x6};
  const int xA0 = (ms * 32 + r) * 128 + xsw;
  const int xA1 = xA0 + 16 * 128;
  const int xB0 = 8192 + (ns * 32 + r) * 128 + xsw;
  const int xB1 = xB0 + 16 * 128;

  auto stageA = [&](int buf, int it) {
    #pragma unroll
    for (int i = 0; i < 2; ++i) {
      int c = i * 256 + tid;
      int row = c >> 3;               // 8 chunks per 128B row
      int colB = (c & 7) * 16;
      int srcB = colB ^ ((row & 7) << 4);
      const char* src = (const char*)(gA + (size_t)row * strideA + it * 64) + srcB;
      gload16(src, smem + buf * 16384 + i * 4096 + w * 1024);
    }
  };
  auto stageB = [&](int buf, int it) {
    #pragma unroll
    for (int i = 0; i < 2; ++i) {
      int c = i * 256 + tid;
      int row = c >> 3;
      int colB = (c & 7) * 16;
      int srcB = colB ^ ((row & 7) << 4);
      const char* src = (const char*)(gB + (size_t)row * NG + it * 64) + srcB;
      gload16(src, smem + buf * 16384 + 8192 + i * 4096 + w * 1024);
    }
  };

  stageA(0, 0); stageB(0, 0);       // 4 ops
  stageA(1, 1); stageB(1, 1);       // 8 ops outstanding

  f32x4 acc00{}, acc01{}, acc10{}, acc11{};
  #pragma unroll
  for (int it = 0; it < 8; ++it) {
    if (it == 7) asm volatile("s_waitcnt vmcnt(0)" ::: "memory");
    else         asm volatile("s_waitcnt vmcnt(4)" ::: "memory");
    __builtin_amdgcn_s_barrier();
    __builtin_amdgcn_sched_barrier(0);
    if (it < 6) { stageA((it + 2) % 3, it + 2); stageB((it + 2) % 3, it + 2); }
    const char* bb = smem + (it % 3) * 16384;
    #pragma unroll
    for (int ks = 0; ks < 2; ++ks) {          // k = it*64 + ks*32 ascending
      bf16x8 a0 = *(const bf16x8*)(bb + xA0 + ksX[ks]);
      bf16x8 a1 = *(const bf16x8*)(bb + xA1 + ksX[ks]);
      bf16x8 b0 = *(const bf16x8*)(bb + xB0 + ksX[ks]);
      bf16x8 b1 = *(const bf16x8*)(bb + xB1 + ksX[ks]);
      acc00 = mfma_bf16(a0, b0, acc00);
      acc01 = mfma_bf16(a0, b1, acc01);
      acc10 = mfma_bf16(a1, b0, acc10);
      acc11 = mfma_bf16(a1, b1, acc11);
    }
  }

  // store partials as bf16: row b = ms*32 + fi*16 + kg*4 + j
  __hip_bfloat16* zb = zpart + ((size_t)(kq * 64 + ms * 32 + kg * 4) << 12)
                     + n0 + ns * 32 + r;
  #pragma unroll
  for (int j = 0; j < 4; ++j) {
    zb[(size_t)j * NG]             = __float2bfloat16(acc00[j]);
    zb[(size_t)j * NG + 16]        = __float2bfloat16(acc01[j]);
    zb[(size_t)(16 + j) * NG]      = __float2bfloat16(acc10[j]);
    zb[(size_t)(16 + j) * NG + 16] = __float2bfloat16(acc11[j]);
  }
}

// ---------------- RNN epilogue: sum bf16 partials + recurrence + relu ---
__global__ __launch_bounds__(256) void rnn_epi_kernel(
    const __hip_bfloat16* __restrict__ zpart,
    const float* __restrict__ v, const float* __restrict__ Win,
    float* __restrict__ vv, float* __restrict__ zp,
    __hip_bfloat16* __restrict__ gs, int t) {
  const int g = blockIdx.x * 256 + threadIdx.x;   // 0..65535
  const int b = g >> 10;
  const int n = (g & 1023) * 4;
  f32x4 s{};
  const unsigned short* zu = (const unsigned short*)zpart;
  #pragma unroll
  for (int kq = 0; kq < 8; ++kq) {                // fixed order: deterministic
    ushort4 u = *(const ushort4*)(zu + ((size_t)(kq * 64 + b) << 12) + n);
    s[0] += __uint_as_float((unsigned)u.x << 16);
    s[1] += __uint_as_float((unsigned)u.y << 16);
    s[2] += __uint_as_float((unsigned)u.z << 16);
    s[3] += __uint_as_float((unsigned)u.w << 16);
  }
  float2 vt = *(const float2*)(v + (b * T_STEPS + t) * 2);
  float4 wA = *(const float4*)(Win + 2 * n);
  float4 wB = *(const float4*)(Win + 2 * n + 4);
  f32x4 z;
  z[0] = s[0] + vt.x * wA.x + vt.y * wA.y;
  z[1] = s[1] + vt.x * wA.z + vt.y * wA.w;
  z[2] = s[2] + vt.x * wB.x + vt.y * wB.y;
  z[3] = s[3] + vt.x * wB.z + vt.y * wB.w;
  f32x4 vvo = *(const f32x4*)(vv + (size_t)b * NG + n);
  f32x4 zpo = *(const f32x4*)(zp + (size_t)b * NG + n);
  union { __hip_bfloat16 h[4]; uint2 u2; } o;
  f32x4 vvn;
  #pragma unroll
  for (int j = 0; j < 4; ++j) {
    z[j] -= 0.5f * vvo[j];                       // z uses OLD vv
    vvn[j] = fmaxf(vvo[j] + 0.1f * (zpo[j] - vvo[j]), 0.f);
    o.h[j] = __float2bfloat16(fmaxf(z[j], 0.f));
  }
  *(f32x4*)(vv + (size_t)b * NG + n) = vvn;
  *(f32x4*)(zp + (size_t)b * NG + n) = z;        // pre-relu z
  *(uint2*)(gs + (size_t)(b * T_STEPS + t) * NG + n) = o.u2;
}

// ---------------- decoder: logits = gs @ W_dec^T, LDS-staged (r12) ------
__global__ __launch_bounds__(256, 4) void decoder_kernel(
    const __hip_bfloat16* __restrict__ gs,
    const __hip_bfloat16* __restrict__ Wd,
    float* __restrict__ out) {
  __shared__ char smem[40960];    // [2 dbuf][A 4KB | B 16KB]
  const int tid = threadIdx.x;
  const int lane = tid & 63;
  const int w = tid >> 6;         // wave = ns (n sub-tile)
  const int bid = blockIdx.x;
  const int xcd = bid & 7;
  const int i6 = bid >> 3;        // 0..99
  const int mtile = xcd * 25 + (i6 % 25);
  const int ntile = i6 / 25;
  const int m0 = mtile * 32;
  const int n0 = ntile * 128;
  const int r = lane & 15;
  const int kg = lane >> 4;

  const __hip_bfloat16* gA = gs + (size_t)m0 * NG;
  const __hip_bfloat16* gB = Wd + (size_t)n0 * NG;

  const int xsw = (kg * 16) ^ ((r & 3) << 4);
  const int x6 = (r & 4) << 4;
  const int ksX[2] = {0 ^ x6, 64 ^ x6};
  const int xA0 = r * 128 + xsw;
  const int xA1 = xA0 + 16 * 128;
  const int xB0 = (w * 32 + r) * 128 + xsw;
  const int xB1 = xB0 + 16 * 128;

  auto stageA = [&](int buf, int it) {
    int row = tid >> 3;
    int colB = (tid & 7) * 16;
    int srcB = colB ^ ((row & 7) << 4);
    const char* src = (const char*)(gA + (size_t)row * NG + it * 64) + srcB;
    gload16(src, smem + buf * 20480 + w * 1024);
  };
  auto stageB = [&](int buf, int it) {
    #pragma unroll
    for (int i = 0; i < 4; ++i) {
      int c = i * 256 + tid;
      int row = c >> 3;
      int colB = (c & 7) * 16;
      int srcB = colB ^ ((row & 7) << 4);
      const char* src = (const char*)(gB + (size_t)row * NG + it * 64) + srcB;
      gload16(src, smem + buf * 20480 + 4096 + i * 4096 + w * 1024);
    }
  };

  stageA(0, 0);
  stageB(0, 0);
  asm volatile("s_waitcnt vmcnt(0)" ::: "memory");
  __syncthreads();

  f32x4 acc00{}, acc01{}, acc10{}, acc11{};
  #pragma unroll 2
  for (int it = 0; it < 64; ++it) {
    const int buf = it & 1;
    if (it < 63) { stageA(buf ^ 1, it + 1); stageB(buf ^ 1, it + 1); }
    const char* bA = smem + buf * 20480;
    const char* bB = bA + 4096;
    #pragma unroll
    for (int ks = 0; ks < 2; ++ks) {
      bf16x8 a0 = *(const bf16x8*)(bA + xA0 + ksX[ks]);
      bf16x8 a1 = *(const bf16x8*)(bA + xA1 + ksX[ks]);
      bf16x8 b0 = *(const bf16x8*)(bB + xB0 + ksX[ks]);
      bf16x8 b1 = *(const bf16x8*)(bB + xB1 + ksX[ks]);
      acc00 = mfma_bf16(a0, b0, acc00);
      acc01 = mfma_bf16(a0, b1, acc01);
      acc10 = mfma_bf16(a1, b0, acc10);
      acc11 = mfma_bf16(a1, b1, acc11);
    }
    asm volatile("s_waitcnt vmcnt(0)" ::: "memory");
    __syncthreads();
  }

  #pragma unroll
  for (int j = 0; j < 4; ++j) {
    float* po0 = out + (size_t)(m0 + kg * 4 + j) * NP + n0 + w * 32;
    float* po1 = out + (size_t)(m0 + 16 + kg * 4 + j) * NP + n0 + w * 32;
    po0[r]      = acc00[j];
    po0[r + 16] = acc01[j];
    po1[r]      = acc10[j];
    po1[r + 16] = acc11[j];
  }
}

// ---------------- log_softmax over rows of 512 (in place) ---------------
__global__ __launch_bounds__(256) void logsoftmax_kernel(float* __restrict__ out) {
  float* row = out + (size_t)blockIdx.x * NP;
  const int tid = threadIdx.x;
  const int lane = tid & 63, wid = tid >> 6;
  float x0 = row[tid], x1 = row[tid + 256];
  float m = fmaxf(x0, x1);
  #pragma unroll
  for (int off = 32; off >= 1; off >>= 1) m = fmaxf(m, __shfl_xor(m, off));
  __shared__ float sred[8];
  if (lane == 0) sred[wid] = m;
  __syncthreads();
  m = fmaxf(fmaxf(sred[0], sred[1]), fmaxf(sred[2], sred[3]));
  float e = __expf(x0 - m) + __expf(x1 - m);
  #pragma unroll
  for (int off = 32; off >= 1; off >>= 1) e += __shfl_xor(e, off);
  if (lane == 0) sred[4 + wid] = e;
  __syncthreads();
  float lse = m + __logf(sred[4] + sred[5] + sred[6] + sred[7]);
  row[tid] = x0 - lse;
  row[tid + 256] = x1 - lse;
}

extern "C" void kernel_launch(void* const* d_in, const int* in_sizes, int n_in,
                              void* d_out, int out_size, void* d_ws, size_t ws_size,
                              hipStream_t stream) {
  const float* v    = (const float*)d_in[0];  // [64,100,2]
  const float* p0   = (const float*)d_in[1];  // [64,512]
  const float* Wenc = (const float*)d_in[2];  // [4096,512]
  const float* Win  = (const float*)d_in[3];  // [4096,2]
  const float* Wh   = (const float*)d_in[4];  // [4096,4096]
  const float* Wdec = (const float*)d_in[5];  // [512,4096]
  float* out = (float*)d_out;                 // [64,100,512]

  char* ws = (char*)d_ws;
  __hip_bfloat16* gs      = (__hip_bfloat16*)(ws);               // 52,428,800
  __hip_bfloat16* Wh_bf   = (__hip_bfloat16*)(ws + 52428800);    // 33,554,432
  __hip_bfloat16* zpart   = (__hip_bfloat16*)(ws + 85983232);    //  4,194,304 (bf16)
  __hip_bfloat16* Wdec_bf = (__hip_bfloat16*)(ws + 85983232);    // aliases zpart (used after RNN)
  float*          vv      = (float*)(ws + 94371840);             //  1,048,576
  float*          zp      = (float*)(ws + 95420416);             //  1,048,576
  __hip_bfloat16* h0_bf   = (__hip_bfloat16*)(ws + 96468992);    //    524,288
  // total 96,993,280 B

  hipMemsetAsync(vv, 0, 2 * 1048576, stream);   // vv + zp (contiguous)
  cvt_bf16_kernel<<<8192, 256, 0, stream>>>(Wh, Wh_bf, 2097152);
  encoder_kernel<<<256, 256, 0, stream>>>(p0, Wenc, h0_bf);

  for (int t = 0; t < T_STEPS; ++t) {
    const __hip_bfloat16* A = (t == 0) ? h0_bf : (gs + (size_t)(t - 1) * NG);
    int sA = (t == 0) ? NG : T_STEPS * NG;
    rnn_gemm_kernel<<<dim3(8, 64), 256, 0, stream>>>(A, sA, Wh_bf, zpart);
    rnn_epi_kernel<<<256, 256, 0, stream>>>(zpart, v, Win, vv, zp, gs, t);
  }

  cvt_bf16_kernel<<<1024, 256, 0, stream>>>(Wdec, Wdec_bf, 262144);  // after RNN (aliases zpart)
  decoder_kernel<<<800, 256, 0, stream>>>(gs, Wdec_bf, out);
  logsoftmax_kernel<<<6400, 256, 0, stream>>>(out);
}

// Round 15
// 1093.382 us; speedup vs baseline: 2.3249x; 1.0323x over previous
//
#include <hip/hip_runtime.h>
#include <hip/hip_bf16.h>

#define T_STEPS 100
#define NG 4096
#define NP 512

typedef __bf16 bf16x8 __attribute__((ext_vector_type(8)));
typedef float f32x4 __attribute__((ext_vector_type(4)));

__device__ __forceinline__ f32x4 mfma_bf16(bf16x8 a, bf16x8 b, f32x4 c) {
  return __builtin_amdgcn_mfma_f32_16x16x32_bf16(a, b, c, 0, 0, 0);
}

// async global->LDS, 16B per lane; LDS dest = wave-uniform base + lane*16
__device__ __forceinline__ void gload16(const void* g, void* l) {
  __builtin_amdgcn_global_load_lds(
      (const __attribute__((address_space(1))) void*)g,
      (__attribute__((address_space(3))) void*)l, 16, 0, 0);
}

__device__ __forceinline__ float bf2f(unsigned short u) {
  return __uint_as_float((unsigned)u << 16);
}

// ---------------- f32 -> bf16 conversion, 8 elems/thread ----------------
__global__ __launch_bounds__(256) void cvt_bf16_kernel(const float* __restrict__ in,
                                                       __hip_bfloat16* __restrict__ out,
                                                       int n8) {
  int i = blockIdx.x * 256 + threadIdx.x;
  if (i >= n8) return;
  const float4* p = reinterpret_cast<const float4*>(in) + (size_t)i * 2;
  float4 f0 = p[0], f1 = p[1];
  union { __hip_bfloat16 h[8]; uint4 u; } z;
  z.h[0] = __float2bfloat16(f0.x); z.h[1] = __float2bfloat16(f0.y);
  z.h[2] = __float2bfloat16(f0.z); z.h[3] = __float2bfloat16(f0.w);
  z.h[4] = __float2bfloat16(f1.x); z.h[5] = __float2bfloat16(f1.y);
  z.h[6] = __float2bfloat16(f1.z); z.h[7] = __float2bfloat16(f1.w);
  *(reinterpret_cast<uint4*>(out) + i) = z.u;
}

// ---------------- encoder: h0 = p0 @ W_enc^T  -> bf16 -------------------
__global__ __launch_bounds__(256) void encoder_kernel(const float* __restrict__ p0,
                                                      const float* __restrict__ Wenc,
                                                      __hip_bfloat16* __restrict__ h0) {
  __shared__ float sp[64 * 129];
  const int tid = threadIdx.x;
  const int nb = blockIdx.x * 16;
  const int b = tid & 63;
  const int jg = tid >> 6;
  float acc[4] = {0.f, 0.f, 0.f, 0.f};
  for (int kc = 0; kc < NP; kc += 128) {
    __syncthreads();
    #pragma unroll
    for (int i = 0; i < 32; ++i) {
      int e = tid + i * 256;
      int bb = e >> 7, kk = e & 127;
      sp[bb * 129 + kk] = p0[bb * NP + kc + kk];
    }
    __syncthreads();
    for (int kk = 0; kk < 128; ++kk) {
      float pv = sp[b * 129 + kk];
      #pragma unroll
      for (int jj = 0; jj < 4; ++jj)
        acc[jj] += pv * Wenc[(size_t)(nb + jg * 4 + jj) * NP + kc + kk];
    }
  }
  #pragma unroll
  for (int jj = 0; jj < 4; ++jj)
    h0[(size_t)b * NG + nb + jg * 4 + jj] = __float2bfloat16(acc[jj]);
}

// ---------------- RNN GEMM partial, 3-buffer ring + counted vmcnt -------
// (round-13/14 structure, frozen; bf16 zpart)
__global__ __launch_bounds__(256, 3) void rnn_gemm_kernel(
    const __hip_bfloat16* __restrict__ A, int strideA,
    const __hip_bfloat16* __restrict__ Wh,
    __hip_bfloat16* __restrict__ zpart) {
  __shared__ char smem[49152];   // [3 bufs][A 8KB | B 8KB]
  const int tid = threadIdx.x;
  const int lane = tid & 63;
  const int w = tid >> 6;
  const int ms = w >> 1, ns = w & 1;
  const int kq = blockIdx.x, ng = blockIdx.y;
  const int r = lane & 15;
  const int kg = lane >> 4;
  const int n0 = ng * 64;

  const __hip_bfloat16* gA = A + (size_t)kq * 512;
  const __hip_bfloat16* gB = Wh + (size_t)n0 * NG + (size_t)kq * 512;

  const int xsw = (kg ^ (r & 3)) << 4;
  const int x6 = (r & 4) << 4;
  const int ksX[2] = {0 ^ x6, 64 ^ x6};
  const int xA0 = (ms * 32 + r) * 128 + xsw;
  const int xA1 = xA0 + 16 * 128;
  const int xB0 = 8192 + (ns * 32 + r) * 128 + xsw;
  const int xB1 = xB0 + 16 * 128;

  auto stageA = [&](int buf, int it) {
    #pragma unroll
    for (int i = 0; i < 2; ++i) {
      int c = i * 256 + tid;
      int row = c >> 3;               // 8 chunks per 128B row
      int colB = (c & 7) * 16;
      int srcB = colB ^ ((row & 7) << 4);
      const char* src = (const char*)(gA + (size_t)row * strideA + it * 64) + srcB;
      gload16(src, smem + buf * 16384 + i * 4096 + w * 1024);
    }
  };
  auto stageB = [&](int buf, int it) {
    #pragma unroll
    for (int i = 0; i < 2; ++i) {
      int c = i * 256 + tid;
      int row = c >> 3;
      int colB = (c & 7) * 16;
      int srcB = colB ^ ((row & 7) << 4);
      const char* src = (const char*)(gB + (size_t)row * NG + it * 64) + srcB;
      gload16(src, smem + buf * 16384 + 8192 + i * 4096 + w * 1024);
    }
  };

  stageA(0, 0); stageB(0, 0);       // 4 ops
  stageA(1, 1); stageB(1, 1);       // 8 ops outstanding

  f32x4 acc00{}, acc01{}, acc10{}, acc11{};
  #pragma unroll
  for (int it = 0; it < 8; ++it) {
    if (it == 7) asm volatile("s_waitcnt vmcnt(0)" ::: "memory");
    else         asm volatile("s_waitcnt vmcnt(4)" ::: "memory");
    __builtin_amdgcn_s_barrier();
    __builtin_amdgcn_sched_barrier(0);
    if (it < 6) { stageA((it + 2) % 3, it + 2); stageB((it + 2) % 3, it + 2); }
    const char* bb = smem + (it % 3) * 16384;
    #pragma unroll
    for (int ks = 0; ks < 2; ++ks) {          // k = it*64 + ks*32 ascending
      bf16x8 a0 = *(const bf16x8*)(bb + xA0 + ksX[ks]);
      bf16x8 a1 = *(const bf16x8*)(bb + xA1 + ksX[ks]);
      bf16x8 b0 = *(const bf16x8*)(bb + xB0 + ksX[ks]);
      bf16x8 b1 = *(const bf16x8*)(bb + xB1 + ksX[ks]);
      acc00 = mfma_bf16(a0, b0, acc00);
      acc01 = mfma_bf16(a0, b1, acc01);
      acc10 = mfma_bf16(a1, b0, acc10);
      acc11 = mfma_bf16(a1, b1, acc11);
    }
  }

  __hip_bfloat16* zb = zpart + ((size_t)(kq * 64 + ms * 32 + kg * 4) << 12)
                     + n0 + ns * 32 + r;
  #pragma unroll
  for (int j = 0; j < 4; ++j) {
    zb[(size_t)j * NG]             = __float2bfloat16(acc00[j]);
    zb[(size_t)j * NG + 16]        = __float2bfloat16(acc01[j]);
    zb[(size_t)(16 + j) * NG]      = __float2bfloat16(acc10[j]);
    zb[(size_t)(16 + j) * NG + 16] = __float2bfloat16(acc11[j]);
  }
}

// ---------------- RNN epilogue: XCD-aligned, bf16 state -----------------
// grid (8 kqg, 32 sub): blockIdx.x = kqg -> XCD = linear%8 = kqg = the XCD
// whose gemm blocks WROTE zpart[.][.][kqg*512..+512) -> L2-local reads.
// Block: b in {2*sub, 2*sub+1}, n-slice [kqg*512, +512); thread = 4 n of 1 b.
// vv/zp state in bf16 (halves state traffic; damped recurrence tolerates).
__global__ __launch_bounds__(256) void rnn_epi_kernel(
    const __hip_bfloat16* __restrict__ zpart,
    const float* __restrict__ v, const float* __restrict__ Win,
    unsigned short* __restrict__ vv, unsigned short* __restrict__ zp,
    __hip_bfloat16* __restrict__ gs, int t) {
  const int kqg = blockIdx.x;
  const int sub = blockIdx.y;
  const int tid = threadIdx.x;
  const int b = sub * 2 + (tid >> 7);
  const int n = kqg * 512 + (tid & 127) * 4;

  f32x4 s{};
  const unsigned short* zu = (const unsigned short*)zpart;
  #pragma unroll
  for (int kq = 0; kq < 8; ++kq) {                // fixed order: deterministic
    ushort4 u = *(const ushort4*)(zu + ((size_t)(kq * 64 + b) << 12) + n);
    s[0] += bf2f(u.x); s[1] += bf2f(u.y); s[2] += bf2f(u.z); s[3] += bf2f(u.w);
  }
  float2 vt = *(const float2*)(v + (b * T_STEPS + t) * 2);
  float4 wA = *(const float4*)(Win + 2 * n);
  float4 wB = *(const float4*)(Win + 2 * n + 4);
  f32x4 z;
  z[0] = s[0] + vt.x * wA.x + vt.y * wA.y;
  z[1] = s[1] + vt.x * wA.z + vt.y * wA.w;
  z[2] = s[2] + vt.x * wB.x + vt.y * wB.y;
  z[3] = s[3] + vt.x * wB.z + vt.y * wB.w;

  const size_t idx = ((size_t)b << 12) + n;
  ushort4 vvu = *(const ushort4*)(vv + idx);
  ushort4 zpu = *(const ushort4*)(zp + idx);
  union { __hip_bfloat16 h[4]; uint2 u2; } og, ov, oz;
  #pragma unroll
  for (int j = 0; j < 4; ++j) {
    float vvo = bf2f(j == 0 ? vvu.x : j == 1 ? vvu.y : j == 2 ? vvu.z : vvu.w);
    float zpo = bf2f(j == 0 ? zpu.x : j == 1 ? zpu.y : j == 2 ? zpu.z : zpu.w);
    z[j] -= 0.5f * vvo;                          // z uses OLD vv
    float vvn = fmaxf(vvo + 0.1f * (zpo - vvo), 0.f);
    ov.h[j] = __float2bfloat16(vvn);
    oz.h[j] = __float2bfloat16(z[j]);            // pre-relu z
    og.h[j] = __float2bfloat16(fmaxf(z[j], 0.f));
  }
  *(uint2*)(vv + idx) = ov.u2;
  *(uint2*)(zp + idx) = oz.u2;
  *(uint2*)(gs + (size_t)(b * T_STEPS + t) * NG + n) = og.u2;
}

// ---------------- decoder: logits = gs @ W_dec^T, LDS-staged (r12) ------
__global__ __launch_bounds__(256, 4) void decoder_kernel(
    const __hip_bfloat16* __restrict__ gs,
    const __hip_bfloat16* __restrict__ Wd,
    float* __restrict__ out) {
  __shared__ char smem[40960];    // [2 dbuf][A 4KB | B 16KB]
  const int tid = threadIdx.x;
  const int lane = tid & 63;
  const int w = tid >> 6;         // wave = ns (n sub-tile)
  const int bid = blockIdx.x;
  const int xcd = bid & 7;
  const int i6 = bid >> 3;        // 0..99
  const int mtile = xcd * 25 + (i6 % 25);
  const int ntile = i6 / 25;
  const int m0 = mtile * 32;
  const int n0 = ntile * 128;
  const int r = lane & 15;
  const int kg = lane >> 4;

  const __hip_bfloat16* gA = gs + (size_t)m0 * NG;
  const __hip_bfloat16* gB = Wd + (size_t)n0 * NG;

  const int xsw = (kg * 16) ^ ((r & 3) << 4);
  const int x6 = (r & 4) << 4;
  const int ksX[2] = {0 ^ x6, 64 ^ x6};
  const int xA0 = r * 128 + xsw;
  const int xA1 = xA0 + 16 * 128;
  const int xB0 = (w * 32 + r) * 128 + xsw;
  const int xB1 = xB0 + 16 * 128;

  auto stageA = [&](int buf, int it) {
    int row = tid >> 3;
    int colB = (tid & 7) * 16;
    int srcB = colB ^ ((row & 7) << 4);
    const char* src = (const char*)(gA + (size_t)row * NG + it * 64) + srcB;
    gload16(src, smem + buf * 20480 + w * 1024);
  };
  auto stageB = [&](int buf, int it) {
    #pragma unroll
    for (int i = 0; i < 4; ++i) {
      int c = i * 256 + tid;
      int row = c >> 3;
      int colB = (c & 7) * 16;
      int srcB = colB ^ ((row & 7) << 4);
      const char* src = (const char*)(gB + (size_t)row * NG + it * 64) + srcB;
      gload16(src, smem + buf * 20480 + 4096 + i * 4096 + w * 1024);
    }
  };

  stageA(0, 0);
  stageB(0, 0);
  asm volatile("s_waitcnt vmcnt(0)" ::: "memory");
  __syncthreads();

  f32x4 acc00{}, acc01{}, acc10{}, acc11{};
  #pragma unroll 2
  for (int it = 0; it < 64; ++it) {
    const int buf = it & 1;
    if (it < 63) { stageA(buf ^ 1, it + 1); stageB(buf ^ 1, it + 1); }
    const char* bA = smem + buf * 20480;
    const char* bB = bA + 4096;
    #pragma unroll
    for (int ks = 0; ks < 2; ++ks) {
      bf16x8 a0 = *(const bf16x8*)(bA + xA0 + ksX[ks]);
      bf16x8 a1 = *(const bf16x8*)(bA + xA1 + ksX[ks]);
      bf16x8 b0 = *(const bf16x8*)(bB + xB0 + ksX[ks]);
      bf16x8 b1 = *(const bf16x8*)(bB + xB1 + ksX[ks]);
      acc00 = mfma_bf16(a0, b0, acc00);
      acc01 = mfma_bf16(a0, b1, acc01);
      acc10 = mfma_bf16(a1, b0, acc10);
      acc11 = mfma_bf16(a1, b1, acc11);
    }
    asm volatile("s_waitcnt vmcnt(0)" ::: "memory");
    __syncthreads();
  }

  #pragma unroll
  for (int j = 0; j < 4; ++j) {
    float* po0 = out + (size_t)(m0 + kg * 4 + j) * NP + n0 + w * 32;
    float* po1 = out + (size_t)(m0 + 16 + kg * 4 + j) * NP + n0 + w * 32;
    po0[r]      = acc00[j];
    po0[r + 16] = acc01[j];
    po1[r]      = acc10[j];
    po1[r + 16] = acc11[j];
  }
}

// ---------------- log_softmax over rows of 512 (in place) ---------------
__global__ __launch_bounds__(256) void logsoftmax_kernel(float* __restrict__ out) {
  float* row = out + (size_t)blockIdx.x * NP;
  const int tid = threadIdx.x;
  const int lane = tid & 63, wid = tid >> 6;
  float x0 = row[tid], x1 = row[tid + 256];
  float m = fmaxf(x0, x1);
  #pragma unroll
  for (int off = 32; off >= 1; off >>= 1) m = fmaxf(m, __shfl_xor(m, off));
  __shared__ float sred[8];
  if (lane == 0) sred[wid] = m;
  __syncthreads();
  m = fmaxf(fmaxf(sred[0], sred[1]), fmaxf(sred[2], sred[3]));
  float e = __expf(x0 - m) + __expf(x1 - m);
  #pragma unroll
  for (int off = 32; off >= 1; off >>= 1) e += __shfl_xor(e, off);
  if (lane == 0) sred[4 + wid] = e;
  __syncthreads();
  float lse = m + __logf(sred[4] + sred[5] + sred[6] + sred[7]);
  row[tid] = x0 - lse;
  row[tid + 256] = x1 - lse;
}

extern "C" void kernel_launch(void* const* d_in, const int* in_sizes, int n_in,
                              void* d_out, int out_size, void* d_ws, size_t ws_size,
                              hipStream_t stream) {
  const float* v    = (const float*)d_in[0];  // [64,100,2]
  const float* p0   = (const float*)d_in[1];  // [64,512]
  const float* Wenc = (const float*)d_in[2];  // [4096,512]
  const float* Win  = (const float*)d_in[3];  // [4096,2]
  const float* Wh   = (const float*)d_in[4];  // [4096,4096]
  const float* Wdec = (const float*)d_in[5];  // [512,4096]
  float* out = (float*)d_out;                 // [64,100,512]

  char* ws = (char*)d_ws;
  __hip_bfloat16* gs      = (__hip_bfloat16*)(ws);               // 52,428,800
  __hip_bfloat16* Wh_bf   = (__hip_bfloat16*)(ws + 52428800);    // 33,554,432
  __hip_bfloat16* zpart   = (__hip_bfloat16*)(ws + 85983232);    //  4,194,304 (bf16)
  __hip_bfloat16* Wdec_bf = (__hip_bfloat16*)(ws + 85983232);    // aliases zpart (used after RNN)
  unsigned short* vv      = (unsigned short*)(ws + 90177536);    //    524,288 (bf16)
  unsigned short* zp      = (unsigned short*)(ws + 90701824);    //    524,288 (bf16)
  __hip_bfloat16* h0_bf   = (__hip_bfloat16*)(ws + 91226112);    //    524,288
  // total 91,750,400 B

  hipMemsetAsync(vv, 0, 1048576, stream);   // vv + zp (contiguous, bf16)
  cvt_bf16_kernel<<<8192, 256, 0, stream>>>(Wh, Wh_bf, 2097152);
  encoder_kernel<<<256, 256, 0, stream>>>(p0, Wenc, h0_bf);

  for (int t = 0; t < T_STEPS; ++t) {
    const __hip_bfloat16* A = (t == 0) ? h0_bf : (gs + (size_t)(t - 1) * NG);
    int sA = (t == 0) ? NG : T_STEPS * NG;
    rnn_gemm_kernel<<<dim3(8, 64), 256, 0, stream>>>(A, sA, Wh_bf, zpart);
    rnn_epi_kernel<<<dim3(8, 32), 256, 0, stream>>>(zpart, v, Win, vv, zp, gs, t);
  }

  cvt_bf16_kernel<<<1024, 256, 0, stream>>>(Wdec, Wdec_bf, 262144);  // after RNN (aliases zpart)
  decoder_kernel<<<800, 256, 0, stream>>>(gs, Wdec_bf, out);
  logsoftmax_kernel<<<6400, 256, 0, stream>>>(out);
}